// Round 1
// baseline (3125.138 us; speedup 1.0000x reference)
//
#include <hip/hip_runtime.h>
#include <math.h>

// ---- problem constants ----
#define B_     4
#define NIMG_  4
#define H_     80
#define W_     80
#define C_     256
#define NH_    8
#define HW_    6400     // H*W
#define NQ_    25600    // NIMG*H*W
#define NPIX_  102400   // B*NQ
#define L3_    200      // 2*10*10 sample points

// ---- workspace layout (float offsets), regions reused across stages ----
#define WS_QKV 0u         // 6,553,600 floats  -> later: q3 @0, kf @3,276,800
#define WS_Q3  0u
#define WS_KF  3276800u
#define WS_FIN 6553600u   // 3,686,400 -> later a2 (3,276,800) -> o3
#define WS_A2  6553600u
#define WS_O3  6553600u
#define WS_OFF 10240000u  // 1,843,200 -> later coords/ks/vs
#define WS_CRD 10240000u
#define WS_KS  10242400u
#define WS_VS  10268000u
#define WS_V2  12083200u  // 3,276,800 -> later vf
#define WS_VF  12083200u
// total = 15,360,000 floats = 61.44 MB

// ============================================================
// K1: qkv = xb @ W_qkv + b_qkv   (rows = b*NQ + n, 64 outputs)
// ============================================================
__global__ __launch_bounds__(256) void k_qkv(const float* __restrict__ x,
        const float* __restrict__ Wq, const float* __restrict__ bq,
        float* __restrict__ qkv) {
    __shared__ __align__(16) float xs[32][256];   // 32 rows staged
    int t = threadIdx.x;
    int row0 = blockIdx.x * 32;
    // cooperative load of 32 rows (x layout: [n][b][c])
    for (int it = 0; it < 8; ++it) {
        int idx = t + it * 256;          // 0..2047 = row(32) * f4(64)
        int r = idx >> 6;
        int f4 = idx & 63;
        int row = row0 + r;
        int b = row / NQ_, n = row % NQ_;
        const float4* src = (const float4*)(x + ((size_t)n * B_ + b) * C_);
        ((float4*)&xs[r][0])[f4] = src[f4];
    }
    __syncthreads();
    int j = t & 63;
    int rbase = (t >> 6) * 8;            // 8 rows per thread
    float acc[8];
    #pragma unroll
    for (int r = 0; r < 8; ++r) acc[r] = 0.f;
    for (int c4 = 0; c4 < 64; ++c4) {
        float w0 = Wq[(c4 * 4 + 0) * 64 + j];
        float w1 = Wq[(c4 * 4 + 1) * 64 + j];
        float w2 = Wq[(c4 * 4 + 2) * 64 + j];
        float w3 = Wq[(c4 * 4 + 3) * 64 + j];
        #pragma unroll
        for (int r = 0; r < 8; ++r) {
            float4 xv = ((const float4*)&xs[rbase + r][0])[c4];
            acc[r] += xv.x * w0 + xv.y * w1 + xv.z * w2 + xv.w * w3;
        }
    }
    float bias = bq[j];
    #pragma unroll
    for (int r = 0; r < 8; ++r) {
        int row = row0 + rbase + r;
        qkv[(size_t)row * 64 + j] = acc[r] + bias;
    }
}

// ============================================================
// K2: fin (36ch, HWC) + v2 (32ch, HWC) per pixel
// fin[k*9+o] = b_fc[o] + sum_c16 W_fc[o,c]*qkv[c*4+k]
// v2[j]      = b_val[j] + sum_c32 qkv[32+c]*W_val[c,j]
// ============================================================
__global__ __launch_bounds__(256) void k_fin_v2(const float* __restrict__ qkv,
        const float* __restrict__ Wfc, const float* __restrict__ bfc,
        const float* __restrict__ Wval, const float* __restrict__ bval,
        float* __restrict__ fin, float* __restrict__ v2) {
    int P = blockIdx.x * 256 + threadIdx.x;      // b*NQ + nq
    int b = P / NQ_, nq = P % NQ_;
    int n = nq / HW_, hw = nq % HW_;
    int bn = b * NIMG_ + n;
    float q[64];
    const float4* qp = (const float4*)(qkv + (size_t)P * 64);
    #pragma unroll
    for (int i = 0; i < 16; ++i) ((float4*)q)[i] = qp[i];
    // fin
    float fo[36];
    #pragma unroll
    for (int k = 0; k < 4; ++k)
        #pragma unroll
        for (int o = 0; o < 9; ++o) fo[k * 9 + o] = bfc[o];
    for (int c = 0; c < 16; ++c) {
        #pragma unroll
        for (int o = 0; o < 9; ++o) {
            float wv = Wfc[o * 16 + c];
            #pragma unroll
            for (int k = 0; k < 4; ++k) fo[k * 9 + o] += wv * q[c * 4 + k];
        }
    }
    float* fp = fin + ((size_t)bn * HW_ + hw) * 36;
    #pragma unroll
    for (int i = 0; i < 9; ++i) ((float4*)fp)[i] = ((float4*)fo)[i];
    // v2
    float vo[32];
    #pragma unroll
    for (int j = 0; j < 32; ++j) vo[j] = bval[j];
    for (int c = 0; c < 32; ++c) {
        float qc = q[32 + c];
        #pragma unroll
        for (int j = 0; j < 32; ++j) vo[j] += qc * Wval[c * 32 + j];
    }
    float* vp = v2 + ((size_t)bn * HW_ + hw) * 32;
    #pragma unroll
    for (int i = 0; i < 8; ++i) ((float4*)vp)[i] = ((float4*)vo)[i];
}

// ============================================================
// K3: off = conv2d(fin, W_doff, pad 1) + b_doff  -> HWC [bn][h][w][18]
// ============================================================
__global__ __launch_bounds__(256) void k_offconv(const float* __restrict__ fin,
        const float* __restrict__ Wdoff, const float* __restrict__ bdoff,
        float* __restrict__ off) {
    __shared__ float Wl[5832];  // reorder [tap][c][o]
    int t = threadIdx.x;
    for (int d = t; d < 5832; d += 256) {
        int tap = d / 648, r = d % 648, c = r / 18, o = r % 18;
        Wl[d] = Wdoff[(o * 36 + c) * 9 + tap];
    }
    __syncthreads();
    int P = blockIdx.x * 256 + t;                // bn*HW + hw
    int bn = P / HW_, hw = P % HW_;
    int h = hw / W_, w = hw % W_;
    float acc[18];
    #pragma unroll
    for (int o = 0; o < 18; ++o) acc[o] = bdoff[o];
    for (int ky = 0; ky < 3; ++ky) {
        int hh = h + ky - 1;
        if (hh < 0 || hh >= H_) continue;
        for (int kx = 0; kx < 3; ++kx) {
            int ww = w + kx - 1;
            if (ww < 0 || ww >= W_) continue;
            const float* base = fin + ((size_t)bn * HW_ + hh * W_ + ww) * 36;
            const float* wl = Wl + (ky * 3 + kx) * 648;
            #pragma unroll
            for (int c4 = 0; c4 < 9; ++c4) {
                float4 v = ((const float4*)base)[c4];
                const float* w0 = wl + (c4 * 4) * 18;
                #pragma unroll
                for (int o = 0; o < 18; ++o)
                    acc[o] += v.x * w0[o] + v.y * w0[18 + o] + v.z * w0[36 + o] + v.w * w0[54 + o];
            }
        }
    }
    float* op = off + (size_t)P * 18;
    #pragma unroll
    for (int o = 0; o < 18; ++o) op[o] = acc[o];
}

// ============================================================
// K4: fused 9-tap bilinear gather + grouped dep einsum + st proj
// thread = (pixel, g);  writes rate2 * out_conv into d_out (full overwrite)
// ============================================================
__global__ __launch_bounds__(256) void k_depst(const float* __restrict__ fin,
        const float* __restrict__ off, const float* __restrict__ Wdep,
        const float* __restrict__ bdep, const float* __restrict__ Wst,
        const float* __restrict__ bst, const float* __restrict__ rate2p,
        float* __restrict__ out) {
    __shared__ float wdep[8748];        // [(g*27+o)*81 + i*9 + k]
    __shared__ float wst[4 * 1736];     // padded per-g stride to break bank aliasing
    int t = threadIdx.x;
    for (int d = t; d < 8748; d += 256) wdep[d] = Wdep[d];
    for (int d = t; d < 6912; d += 256) {
        int g = d / 1728, r = d % 1728;
        wst[g * 1736 + r] = Wst[d];
    }
    __syncthreads();
    int T = blockIdx.x * 256 + t;
    int P = T >> 2, g = T & 3;
    int bn = P / HW_, hw = P % HW_;
    int h = hw / W_, w = hw % W_;
    int b = bn >> 2, n = bn & 3;
    const float* offp = off + (size_t)P * 18;
    const float* finb = fin + (size_t)bn * HW_ * 36 + g * 9;
    float acc[27];
    #pragma unroll
    for (int o = 0; o < 27; ++o) acc[o] = 0.f;
    #pragma unroll
    for (int k = 0; k < 9; ++k) {
        float py = (float)h + (float)(k / 3 - 1) + offp[k * 2 + 0];
        float px = (float)w + (float)(k % 3 - 1) + offp[k * 2 + 1];
        float y0 = floorf(py), x0 = floorf(px);
        float wy = py - y0, wx = px - x0;
        float s[9];
        #pragma unroll
        for (int i = 0; i < 9; ++i) s[i] = 0.f;
        #pragma unroll
        for (int cy = 0; cy < 2; ++cy) {
            float yf = y0 + (float)cy;
            if (yf < 0.f || yf > 79.f) continue;
            float wyf = cy ? wy : 1.f - wy;
            int yi = (int)yf;
            #pragma unroll
            for (int cx = 0; cx < 2; ++cx) {
                float xf = x0 + (float)cx;
                if (xf < 0.f || xf > 79.f) continue;
                float wgt = wyf * (cx ? wx : 1.f - wx);
                int xi = (int)xf;
                const float* cp = finb + ((size_t)yi * W_ + xi) * 36;
                #pragma unroll
                for (int i = 0; i < 9; ++i) s[i] += wgt * cp[i];
            }
        }
        const float* wd = wdep + g * 2187 + k;
        #pragma unroll
        for (int i = 0; i < 9; ++i) {
            float sv = s[i];
            #pragma unroll
            for (int o = 0; o < 27; ++o) acc[o] += sv * wd[(o * 9 + i) * 9];
        }
    }
    #pragma unroll
    for (int i = 0; i < 27; ++i) acc[i] += bdep[g * 27 + i];
    float r2 = rate2p[0];
    const float* wstg = wst + g * 1736;
    float* ob = out + ((size_t)(n * HW_ + hw) * B_ + b) * C_ + g * 64;
    for (int o4 = 0; o4 < 16; ++o4) {
        float res[4];
        #pragma unroll
        for (int qq = 0; qq < 4; ++qq) {
            int o = o4 * 4 + qq;
            float a = bst[g * 64 + o];
            #pragma unroll
            for (int i = 0; i < 27; ++i) a += acc[i] * wstg[o * 27 + i];
            res[qq] = r2 * a;
        }
        ((float4*)ob)[o4] = make_float4(res[0], res[1], res[2], res[3]);
    }
}

// ============================================================
// K5: 2D deformable attention -> a2 (post W_out2d), HWC [bn][hw][32]
// ============================================================
__global__ __launch_bounds__(256) void k_attn2d(const float* __restrict__ qkv,
        const float* __restrict__ v2,
        const float* __restrict__ Woff, const float* __restrict__ boff,
        const float* __restrict__ Watt, const float* __restrict__ batt,
        const float* __restrict__ Wout, const float* __restrict__ bout,
        float* __restrict__ a2) {
    int P = blockIdx.x * 256 + threadIdx.x;      // b*NQ + nq
    int b = P / NQ_, nq = P % NQ_;
    int n = nq / HW_, hw = nq % HW_;
    int h = hw / W_, w = hw % W_;
    int bn = b * NIMG_ + n;
    float q[32];
    const float4* qp = (const float4*)(qkv + (size_t)P * 64);
    #pragma unroll
    for (int i = 0; i < 8; ++i) ((float4*)q)[i] = qp[i];
    const float* vbase = v2 + (size_t)bn * HW_ * 32;
    float a2v[32];
    #pragma unroll
    for (int i = 0; i < 32; ++i) a2v[i] = 0.f;
    for (int nh = 0; nh < 8; ++nh) {
        float t0 = batt[nh * 4 + 0], t1 = batt[nh * 4 + 1];
        float t2 = batt[nh * 4 + 2], t3 = batt[nh * 4 + 3];
        for (int c = 0; c < 32; ++c) {
            float qc = q[c];
            const float* wr = Watt + c * 32 + nh * 4;
            t0 += qc * wr[0]; t1 += qc * wr[1]; t2 += qc * wr[2]; t3 += qc * wr[3];
        }
        float m = fmaxf(fmaxf(t0, t1), fmaxf(t2, t3));
        float e0 = expf(t0 - m), e1 = expf(t1 - m), e2 = expf(t2 - m), e3 = expf(t3 - m);
        float inv = 1.f / (e0 + e1 + e2 + e3);
        float pk[4] = {e0 * inv, e1 * inv, e2 * inv, e3 * inv};
        #pragma unroll
        for (int kk = 0; kk < 4; ++kk) {
            int j0 = nh * 8 + kk * 2;
            float ox = boff[j0], oy = boff[j0 + 1];
            for (int c = 0; c < 32; ++c) {
                float qc = q[c];
                ox += qc * Woff[c * 64 + j0];
                oy += qc * Woff[c * 64 + j0 + 1];
            }
            float ppx = (float)w + ox * (79.f / 80.f);
            float ppy = (float)h + oy * (79.f / 80.f);
            float x0 = floorf(ppx), y0 = floorf(ppy);
            float wx = ppx - x0, wy = ppy - y0;
            float s0 = 0.f, s1 = 0.f, s2 = 0.f, s3 = 0.f;
            #pragma unroll
            for (int cy = 0; cy < 2; ++cy) {
                float yf = y0 + (float)cy;
                if (yf < 0.f || yf > 79.f) continue;
                float wyf = cy ? wy : 1.f - wy;
                int yi = (int)yf;
                #pragma unroll
                for (int cx = 0; cx < 2; ++cx) {
                    float xf = x0 + (float)cx;
                    if (xf < 0.f || xf > 79.f) continue;
                    float wgt = wyf * (cx ? wx : 1.f - wx);
                    int xi = (int)xf;
                    float4 vv = *(const float4*)(vbase + ((size_t)yi * W_ + xi) * 32 + nh * 4);
                    s0 += wgt * vv.x; s1 += wgt * vv.y; s2 += wgt * vv.z; s3 += wgt * vv.w;
                }
            }
            float p = pk[kk];
            a2v[nh * 4 + 0] += p * s0; a2v[nh * 4 + 1] += p * s1;
            a2v[nh * 4 + 2] += p * s2; a2v[nh * 4 + 3] += p * s3;
        }
    }
    float ro[32];
    #pragma unroll
    for (int o = 0; o < 32; ++o) ro[o] = bout[o];
    for (int c = 0; c < 32; ++c) {
        float ac = a2v[c];
        const float* wr = Wout + c * 32;
        #pragma unroll
        for (int o = 0; o < 32; ++o) ro[o] += ac * wr[o];
    }
    float* op = a2 + ((size_t)bn * HW_ + hw) * 32;
    #pragma unroll
    for (int i = 0; i < 8; ++i) ((float4*)op)[i] = ((float4*)ro)[i];
}

// ============================================================
// K6: q3/kf/vf = 32->32 projections of x3 (frame-concat bug: src = n==0?0:n-1)
// ============================================================
__global__ __launch_bounds__(256) void k_qkv3(const float* __restrict__ a2,
        const float* __restrict__ Wq3, const float* __restrict__ bq3,
        const float* __restrict__ Wk3, const float* __restrict__ bk3,
        const float* __restrict__ Wv3, const float* __restrict__ bv3,
        float* __restrict__ q3, float* __restrict__ kf, float* __restrict__ vf) {
    int idx = blockIdx.x * 256 + threadIdx.x;    // (b*4+n)*HW + hw
    int bn = idx / HW_, hw = idx % HW_;
    int b = bn >> 2, n = bn & 3;
    int ns = (n == 0) ? 0 : n - 1;
    const float* src = a2 + ((size_t)(b * 4 + ns) * HW_ + hw) * 32;
    float v[32];
    #pragma unroll
    for (int i = 0; i < 8; ++i) ((float4*)v)[i] = ((const float4*)src)[i];
    float oq[32], ok[32], ov[32];
    #pragma unroll
    for (int o = 0; o < 32; ++o) {
        float aq = bq3[o], ak = bk3[o], av = bv3[o];
        #pragma unroll
        for (int c = 0; c < 32; ++c) {
            aq += Wq3[o * 32 + c] * v[c];
            ak += Wk3[o * 32 + c] * v[c];
            av += Wv3[o * 32 + c] * v[c];
        }
        oq[o] = aq; ok[o] = ak; ov[o] = av;
    }
    float* qo = q3 + (size_t)idx * 32;
    float* ko = kf + (size_t)idx * 32;
    float* vo = vf + (size_t)idx * 32;
    #pragma unroll
    for (int i = 0; i < 8; ++i) {
        ((float4*)qo)[i] = ((float4*)oq)[i];
        ((float4*)ko)[i] = ((float4*)ok)[i];
        ((float4*)vo)[i] = ((float4*)ov)[i];
    }
}

// ============================================================
// K7: strided conv3d (W_offA) + gelu + W_offB + tanh*OSC -> sample coords
// one block per (zo,ho,wo), all 4 batches; coords [b][200][3]
// ============================================================
__global__ __launch_bounds__(256) void k_offs3d(const float* __restrict__ q3,
        const float* __restrict__ WoffA, const float* __restrict__ boffA,
        const float* __restrict__ WoffB, const float* __restrict__ boffB,
        float* __restrict__ coords) {
    __shared__ float red[4][128];
    __shared__ float hidl[128];
    int t = threadIdx.x;
    int blk = blockIdx.x;                       // zo*100+ho*10+wo
    int zo = blk / 100, r = blk % 100, ho = r / 10, wo = r % 10;
    float acc[4][32];
    #pragma unroll
    for (int b = 0; b < 4; ++b)
        #pragma unroll
        for (int o = 0; o < 32; ++o) acc[b][o] = 0.f;
    for (int tap = t; tap < 400; tap += 256) {
        int kz = tap / 100, r2 = tap % 100, ky = r2 / 10, kx = r2 % 10;
        int zi = zo * 2 + kz - 1, hi = ho * 8 + ky - 1, wi = wo * 8 + kx - 1;
        if (zi < 0 || zi >= NIMG_ || hi < 0 || hi >= H_ || wi < 0 || wi >= W_) continue;
        const float* wb = WoffA + tap;
        int sp = hi * W_ + wi;
        for (int c = 0; c < 32; ++c) {
            float vb[4];
            #pragma unroll
            for (int b = 0; b < 4; ++b)
                vb[b] = q3[((size_t)(b * 4 + zi) * HW_ + sp) * 32 + c];
            #pragma unroll
            for (int o = 0; o < 32; ++o) {
                float wv = wb[(o * 32 + c) * 400];
                #pragma unroll
                for (int b = 0; b < 4; ++b) acc[b][o] += vb[b] * wv;
            }
        }
    }
    // wave butterfly reduce, then cross-wave via LDS
    #pragma unroll
    for (int b = 0; b < 4; ++b)
        #pragma unroll
        for (int o = 0; o < 32; ++o)
            for (int sh = 32; sh >= 1; sh >>= 1)
                acc[b][o] += __shfl_xor(acc[b][o], sh);
    int lane = t & 63, wv = t >> 6;
    if (lane == 0)
        for (int b = 0; b < 4; ++b)
            for (int o = 0; o < 32; ++o) red[wv][b * 32 + o] = acc[b][o];
    __syncthreads();
    if (t < 128) {
        float v = red[0][t] + red[1][t] + red[2][t] + red[3][t] + boffA[t & 31];
        float v3 = v * v * v;
        hidl[t] = 0.5f * v * (1.f + tanhf(0.7978845608028654f * (v + 0.044715f * v3)));
    }
    __syncthreads();
    if (t < 12) {
        int b = t / 3, j = t % 3;
        float a = boffB[j];
        for (int o = 0; o < 32; ++o) a += WoffB[j * 32 + o] * hidl[b * 32 + o];
        float osc = (j == 0) ? 2.f : 8.f;
        float base = (j == 0) ? (zo * 2 + 0.5f) : ((j == 1) ? (ho * 8 + 3.5f) : (wo * 8 + 3.5f));
        coords[((size_t)b * L3_ + blk) * 3 + j] = base + tanhf(a) * osc;
    }
}

// ============================================================
// K8: trilinear sample kf/vf at coords -> ks/vs [b][200][32]
// one wave per (b, point); lanes 0-31 do ks, 32-63 do vs
// ============================================================
__global__ __launch_bounds__(256) void k_trisample(const float* __restrict__ kf,
        const float* __restrict__ vf, const float* __restrict__ coords,
        float* __restrict__ ks, float* __restrict__ vs) {
    int t = threadIdx.x;
    int wv = blockIdx.x * 4 + (t >> 6);          // 0..799
    int b = wv / L3_, l = wv % L3_;
    int lane = t & 63;
    int c = lane & 31;
    const float* src = (lane < 32) ? kf : vf;
    float* dst = (lane < 32) ? ks : vs;
    const float* cp = coords + ((size_t)b * L3_ + l) * 3;
    float cz = cp[0], cy = cp[1], cx = cp[2];
    float z0 = floorf(cz), y0 = floorf(cy), x0 = floorf(cx);
    float wz = cz - z0, wy = cy - y0, wx = cx - x0;
    float acc = 0.f;
    #pragma unroll
    for (int dz = 0; dz < 2; ++dz) {
        float zf = z0 + (float)dz;
        if (zf < 0.f || zf > 3.f) continue;
        float wzf = dz ? wz : 1.f - wz;
        int zi = (int)zf;
        #pragma unroll
        for (int dy = 0; dy < 2; ++dy) {
            float yf = y0 + (float)dy;
            if (yf < 0.f || yf > 79.f) continue;
            float wyf = wzf * (dy ? wy : 1.f - wy);
            int yi = (int)yf;
            #pragma unroll
            for (int dx = 0; dx < 2; ++dx) {
                float xf = x0 + (float)dx;
                if (xf < 0.f || xf > 79.f) continue;
                float wgt = wyf * (dx ? wx : 1.f - wx);
                int xi = (int)xf;
                acc += wgt * src[((size_t)(b * 4 + zi) * HW_ + yi * W_ + xi) * 32 + c];
            }
        }
    }
    dst[((size_t)b * L3_ + l) * 32 + c] = acc;
}

// ============================================================
// K9: 25600-query x 200-key attention per batch -> o3 [b][N][32]
// ks/vs staged in LDS; all threads of a block share one batch
// ============================================================
__global__ __launch_bounds__(256) void k_attn3d(const float* __restrict__ q3,
        const float* __restrict__ ks, const float* __restrict__ vs,
        float* __restrict__ o3) {
    __shared__ __align__(16) float ksl[L3_ * 32];
    __shared__ __align__(16) float vsl[L3_ * 32];
    int t = threadIdx.x;
    int b = blockIdx.x / 100;
    int chunk = blockIdx.x % 100;
    const float4* ksg = (const float4*)(ks + (size_t)b * L3_ * 32);
    const float4* vsg = (const float4*)(vs + (size_t)b * L3_ * 32);
    for (int d = t; d < L3_ * 8; d += 256) {
        ((float4*)ksl)[d] = ksg[d];
        ((float4*)vsl)[d] = vsg[d];
    }
    __syncthreads();
    int N = chunk * 256 + t;
    float q[32];
    const float4* qp = (const float4*)(q3 + ((size_t)b * NQ_ + N) * 32);
    #pragma unroll
    for (int i = 0; i < 8; ++i) ((float4*)q)[i] = qp[i];
    const float scale = 0.17677669529663687f;    // 32^-0.5
    float m = -1e30f;
    for (int l = 0; l < L3_; ++l) {
        const float4* kp = (const float4*)(ksl + l * 32);
        float s = 0.f;
        #pragma unroll
        for (int c4 = 0; c4 < 8; ++c4) {
            float4 kv = kp[c4];
            s += q[c4 * 4 + 0] * kv.x + q[c4 * 4 + 1] * kv.y + q[c4 * 4 + 2] * kv.z + q[c4 * 4 + 3] * kv.w;
        }
        m = fmaxf(m, s);
    }
    m *= scale;
    float den = 0.f;
    float o[32];
    #pragma unroll
    for (int c = 0; c < 32; ++c) o[c] = 0.f;
    for (int l = 0; l < L3_; ++l) {
        const float4* kp = (const float4*)(ksl + l * 32);
        float s = 0.f;
        #pragma unroll
        for (int c4 = 0; c4 < 8; ++c4) {
            float4 kv = kp[c4];
            s += q[c4 * 4 + 0] * kv.x + q[c4 * 4 + 1] * kv.y + q[c4 * 4 + 2] * kv.z + q[c4 * 4 + 3] * kv.w;
        }
        float p = expf(s * scale - m);
        den += p;
        const float4* vp = (const float4*)(vsl + l * 32);
        #pragma unroll
        for (int c4 = 0; c4 < 8; ++c4) {
            float4 vv = vp[c4];
            o[c4 * 4 + 0] += p * vv.x; o[c4 * 4 + 1] += p * vv.y;
            o[c4 * 4 + 2] += p * vv.z; o[c4 * 4 + 3] += p * vv.w;
        }
    }
    float inv = 1.f / den;
    float* op = o3 + ((size_t)b * NQ_ + N) * 32;
    #pragma unroll
    for (int c = 0; c < 32; ++c) op[c] = o[c] * inv;
}

// ============================================================
// K10: out += rate1 * (W_out3 @ o3 + b_out3)   (block = (N,b), thread = ch)
// ============================================================
__global__ __launch_bounds__(256) void k_final(const float* __restrict__ o3,
        const float* __restrict__ W, const float* __restrict__ bias,
        const float* __restrict__ r1p, float* __restrict__ out) {
    int blk = blockIdx.x, t = threadIdx.x;       // blk = N*4 + b
    int b = blk & 3, N = blk >> 2;
    const float4* ovp = (const float4*)(o3 + ((size_t)b * NQ_ + N) * 32);
    float v[32];
    #pragma unroll
    for (int i = 0; i < 8; ++i) ((float4*)v)[i] = ovp[i];
    float a = bias[t];
    const float* wr = W + t * 32;
    #pragma unroll
    for (int c = 0; c < 32; ++c) a += v[c] * wr[c];
    size_t oi = (size_t)blk * 256 + t;
    out[oi] = r1p[0] * a + out[oi];
}

// ============================================================
extern "C" void kernel_launch(void* const* d_in, const int* in_sizes, int n_in,
                              void* d_out, int out_size, void* d_ws, size_t ws_size,
                              hipStream_t stream) {
    (void)in_sizes; (void)n_in; (void)out_size; (void)ws_size;
    const float* x      = (const float*)d_in[0];
    const float* W_qkv  = (const float*)d_in[1];
    const float* b_qkv  = (const float*)d_in[2];
    const float* W_fc   = (const float*)d_in[3];
    const float* b_fc   = (const float*)d_in[4];
    const float* W_doff = (const float*)d_in[5];
    const float* b_doff = (const float*)d_in[6];
    const float* W_dep  = (const float*)d_in[7];
    const float* b_dep  = (const float*)d_in[8];
    const float* W_st   = (const float*)d_in[9];
    const float* b_st   = (const float*)d_in[10];
    const float* W_off2d= (const float*)d_in[11];
    const float* b_off2d= (const float*)d_in[12];
    const float* W_attw = (const float*)d_in[13];
    const float* b_attw = (const float*)d_in[14];
    const float* W_val  = (const float*)d_in[15];
    const float* b_val  = (const float*)d_in[16];
    const float* W_out2d= (const float*)d_in[17];
    const float* b_out2d= (const float*)d_in[18];
    const float* W_q3   = (const float*)d_in[19];
    const float* b_q3   = (const float*)d_in[20];
    const float* W_k3   = (const float*)d_in[21];
    const float* b_k3   = (const float*)d_in[22];
    const float* W_v3   = (const float*)d_in[23];
    const float* b_v3   = (const float*)d_in[24];
    const float* W_offA = (const float*)d_in[25];
    const float* b_offA = (const float*)d_in[26];
    const float* W_offB = (const float*)d_in[27];
    const float* b_offB = (const float*)d_in[28];
    const float* W_out3 = (const float*)d_in[29];
    const float* b_out3 = (const float*)d_in[30];
    const float* rate1  = (const float*)d_in[31];
    const float* rate2  = (const float*)d_in[32];

    float* ws  = (float*)d_ws;
    float* out = (float*)d_out;
    float* qkv = ws + WS_QKV;
    float* fin = ws + WS_FIN;
    float* off = ws + WS_OFF;
    float* v2  = ws + WS_V2;
    float* a2  = ws + WS_A2;
    float* q3  = ws + WS_Q3;
    float* kf  = ws + WS_KF;
    float* vf  = ws + WS_VF;
    float* crd = ws + WS_CRD;
    float* ks  = ws + WS_KS;
    float* vs  = ws + WS_VS;
    float* o3w = ws + WS_O3;

    k_qkv      <<<3200,   256, 0, stream>>>(x, W_qkv, b_qkv, qkv);
    k_fin_v2   <<<400,    256, 0, stream>>>(qkv, W_fc, b_fc, W_val, b_val, fin, v2);
    k_offconv  <<<400,    256, 0, stream>>>(fin, W_doff, b_doff, off);
    k_depst    <<<1600,   256, 0, stream>>>(fin, off, W_dep, b_dep, W_st, b_st, rate2, out);
    k_attn2d   <<<400,    256, 0, stream>>>(qkv, v2, W_off2d, b_off2d, W_attw, b_attw, W_out2d, b_out2d, a2);
    k_qkv3     <<<400,    256, 0, stream>>>(a2, W_q3, b_q3, W_k3, b_k3, W_v3, b_v3, q3, kf, vf);
    k_offs3d   <<<200,    256, 0, stream>>>(q3, W_offA, b_offA, W_offB, b_offB, crd);
    k_trisample<<<200,    256, 0, stream>>>(kf, vf, crd, ks, vs);
    k_attn3d   <<<400,    256, 0, stream>>>(q3, ks, vs, o3w);
    k_final    <<<102400, 256, 0, stream>>>(o3w, W_out3, b_out3, rate1, out);
}

// Round 2
// 1300.513 us; speedup vs baseline: 2.4030x; 2.4030x over previous
//
#include <hip/hip_runtime.h>
#include <math.h>

// ---- problem constants ----
#define B_     4
#define NIMG_  4
#define H_     80
#define W_     80
#define C_     256
#define NH_    8
#define HW_    6400     // H*W
#define NQ_    25600    // NIMG*H*W
#define NPIX_  102400   // B*NQ
#define L3_    200      // 2*10*10 sample points

// ---- workspace layout (float offsets), regions reused across stages ----
#define WS_QKV 0u         // 6,553,600 floats  -> later: q3 @0, kf @3,276,800
#define WS_Q3  0u
#define WS_KF  3276800u
#define WS_FIN 6553600u   // 3,686,400 -> later a2 (3,276,800) -> o3
#define WS_A2  6553600u
#define WS_O3  6553600u
#define WS_OFF 10240000u  // 1,843,200 -> later coords/ks/vs
#define WS_CRD 10240000u
#define WS_KS  10242400u
#define WS_VS  10268000u
#define WS_V2  12083200u  // 3,276,800 -> later vf
#define WS_VF  12083200u
// total = 15,360,000 floats = 61.44 MB

// ============================================================
// K1: qkv = xb @ W_qkv + b_qkv   (rows = b*NQ + n, 64 outputs)
// ============================================================
__global__ __launch_bounds__(256) void k_qkv(const float* __restrict__ x,
        const float* __restrict__ Wq, const float* __restrict__ bq,
        float* __restrict__ qkv) {
    __shared__ __align__(16) float xs[32][256];   // 32 rows staged
    int t = threadIdx.x;
    int row0 = blockIdx.x * 32;
    // cooperative load of 32 rows (x layout: [n][b][c])
    for (int it = 0; it < 8; ++it) {
        int idx = t + it * 256;          // 0..2047 = row(32) * f4(64)
        int r = idx >> 6;
        int f4 = idx & 63;
        int row = row0 + r;
        int b = row / NQ_, n = row % NQ_;
        const float4* src = (const float4*)(x + ((size_t)n * B_ + b) * C_);
        ((float4*)&xs[r][0])[f4] = src[f4];
    }
    __syncthreads();
    int j = t & 63;
    int rbase = (t >> 6) * 8;            // 8 rows per thread
    float acc[8];
    #pragma unroll
    for (int r = 0; r < 8; ++r) acc[r] = 0.f;
    for (int c4 = 0; c4 < 64; ++c4) {
        float w0 = Wq[(c4 * 4 + 0) * 64 + j];
        float w1 = Wq[(c4 * 4 + 1) * 64 + j];
        float w2 = Wq[(c4 * 4 + 2) * 64 + j];
        float w3 = Wq[(c4 * 4 + 3) * 64 + j];
        #pragma unroll
        for (int r = 0; r < 8; ++r) {
            float4 xv = ((const float4*)&xs[rbase + r][0])[c4];
            acc[r] += xv.x * w0 + xv.y * w1 + xv.z * w2 + xv.w * w3;
        }
    }
    float bias = bq[j];
    #pragma unroll
    for (int r = 0; r < 8; ++r) {
        int row = row0 + rbase + r;
        qkv[(size_t)row * 64 + j] = acc[r] + bias;
    }
}

// ============================================================
// K2: fin (36ch, HWC) + v2 (32ch, HWC) per pixel
// ============================================================
__global__ __launch_bounds__(256) void k_fin_v2(const float* __restrict__ qkv,
        const float* __restrict__ Wfc, const float* __restrict__ bfc,
        const float* __restrict__ Wval, const float* __restrict__ bval,
        float* __restrict__ fin, float* __restrict__ v2) {
    int P = blockIdx.x * 256 + threadIdx.x;      // b*NQ + nq
    int b = P / NQ_, nq = P % NQ_;
    int n = nq / HW_, hw = nq % HW_;
    int bn = b * NIMG_ + n;
    float q[64];
    const float4* qp = (const float4*)(qkv + (size_t)P * 64);
    #pragma unroll
    for (int i = 0; i < 16; ++i) ((float4*)q)[i] = qp[i];
    // fin
    float fo[36];
    #pragma unroll
    for (int k = 0; k < 4; ++k)
        #pragma unroll
        for (int o = 0; o < 9; ++o) fo[k * 9 + o] = bfc[o];
    for (int c = 0; c < 16; ++c) {
        #pragma unroll
        for (int o = 0; o < 9; ++o) {
            float wv = Wfc[o * 16 + c];
            #pragma unroll
            for (int k = 0; k < 4; ++k) fo[k * 9 + o] += wv * q[c * 4 + k];
        }
    }
    float* fp = fin + ((size_t)bn * HW_ + hw) * 36;
    #pragma unroll
    for (int i = 0; i < 9; ++i) ((float4*)fp)[i] = ((float4*)fo)[i];
    // v2
    float vo[32];
    #pragma unroll
    for (int j = 0; j < 32; ++j) vo[j] = bval[j];
    for (int c = 0; c < 32; ++c) {
        float qc = q[32 + c];
        #pragma unroll
        for (int j = 0; j < 32; ++j) vo[j] += qc * Wval[c * 32 + j];
    }
    float* vp = v2 + ((size_t)bn * HW_ + hw) * 32;
    #pragma unroll
    for (int i = 0; i < 8; ++i) ((float4*)vp)[i] = ((float4*)vo)[i];
}

// ============================================================
// K3: off = conv2d(fin, W_doff, pad 1) + b_doff  -> HWC [bn][h][w][18]
// ============================================================
__global__ __launch_bounds__(256) void k_offconv(const float* __restrict__ fin,
        const float* __restrict__ Wdoff, const float* __restrict__ bdoff,
        float* __restrict__ off) {
    __shared__ float Wl[5832];  // reorder [tap][c][o]
    int t = threadIdx.x;
    for (int d = t; d < 5832; d += 256) {
        int tap = d / 648, r = d % 648, c = r / 18, o = r % 18;
        Wl[d] = Wdoff[(o * 36 + c) * 9 + tap];
    }
    __syncthreads();
    int P = blockIdx.x * 256 + t;                // bn*HW + hw
    int bn = P / HW_, hw = P % HW_;
    int h = hw / W_, w = hw % W_;
    float acc[18];
    #pragma unroll
    for (int o = 0; o < 18; ++o) acc[o] = bdoff[o];
    for (int ky = 0; ky < 3; ++ky) {
        int hh = h + ky - 1;
        if (hh < 0 || hh >= H_) continue;
        for (int kx = 0; kx < 3; ++kx) {
            int ww = w + kx - 1;
            if (ww < 0 || ww >= W_) continue;
            const float* base = fin + ((size_t)bn * HW_ + hh * W_ + ww) * 36;
            const float* wl = Wl + (ky * 3 + kx) * 648;
            #pragma unroll
            for (int c4 = 0; c4 < 9; ++c4) {
                float4 v = ((const float4*)base)[c4];
                const float* w0 = wl + (c4 * 4) * 18;
                #pragma unroll
                for (int o = 0; o < 18; ++o)
                    acc[o] += v.x * w0[o] + v.y * w0[18 + o] + v.z * w0[36 + o] + v.w * w0[54 + o];
            }
        }
    }
    float* op = off + (size_t)P * 18;
    #pragma unroll
    for (int o = 0; o < 18; ++o) op[o] = acc[o];
}

// ============================================================
// K4: fused 9-tap bilinear gather + grouped dep einsum + st proj
// R2: register-pressure surgery. Tap loop NOT unrolled; wdep in LDS
// re-laid as [g][k][o][i] (contiguous inner reads); launch_bounds(256,4)
// caps VGPRs at 128 (R1: 256 VGPR + 2.6 GB scratch-spill writes).
// ============================================================
__global__ __launch_bounds__(256, 4) void k_depst(const float* __restrict__ fin,
        const float* __restrict__ off, const float* __restrict__ Wdep,
        const float* __restrict__ bdep, const float* __restrict__ Wst,
        const float* __restrict__ bst, const float* __restrict__ rate2p,
        float* __restrict__ out) {
    __shared__ float wdepL[8748];       // [((g*9+k)*27+o)*9+i]
    __shared__ float wst[4 * 1736];     // padded per-g stride (1736 mod 32 = 8)
    int t = threadIdx.x;
    for (int d = t; d < 8748; d += 256) {
        int i = d % 9, o = (d / 9) % 27, k = (d / 243) % 9, g = d / 2187;
        wdepL[d] = Wdep[(size_t)(g * 27 + o) * 81 + i * 9 + k];
    }
    for (int d = t; d < 6912; d += 256) {
        int g = d / 1728, r = d % 1728;
        wst[g * 1736 + r] = Wst[d];
    }
    __syncthreads();
    int T = blockIdx.x * 256 + t;
    int P = T >> 2, g = T & 3;
    int bn = P / HW_, hw = P % HW_;
    int h = hw / W_, w = hw % W_;
    int b = bn >> 2, n = bn & 3;
    // preload the 18 offsets once
    float offs[18];
    const float* offp = off + (size_t)P * 18;
    #pragma unroll
    for (int i = 0; i < 18; ++i) offs[i] = offp[i];
    const float* finb = fin + (size_t)bn * HW_ * 36 + g * 9;
    float acc[27];
    #pragma unroll
    for (int o = 0; o < 27; ++o) acc[o] = 0.f;
    #pragma unroll 1
    for (int k = 0; k < 9; ++k) {
        float py = (float)h + (float)(k / 3 - 1) + offs[k * 2 + 0];
        float px = (float)w + (float)(k % 3 - 1) + offs[k * 2 + 1];
        float y0 = floorf(py), x0 = floorf(px);
        float wy = py - y0, wx = px - x0;
        float s[9];
        #pragma unroll
        for (int i = 0; i < 9; ++i) s[i] = 0.f;
        #pragma unroll 1
        for (int cy = 0; cy < 2; ++cy) {
            float yf = y0 + (float)cy;
            if (yf < 0.f || yf > 79.f) continue;
            float wyf = cy ? wy : 1.f - wy;
            int yi = (int)yf;
            #pragma unroll 1
            for (int cx = 0; cx < 2; ++cx) {
                float xf = x0 + (float)cx;
                if (xf < 0.f || xf > 79.f) continue;
                float wgt = wyf * (cx ? wx : 1.f - wx);
                int xi = (int)xf;
                const float* cp = finb + ((size_t)yi * W_ + xi) * 36;
                #pragma unroll
                for (int i = 0; i < 9; ++i) s[i] += wgt * cp[i];
            }
        }
        const float* wd = wdepL + (g * 9 + k) * 243;
        #pragma unroll
        for (int o = 0; o < 27; ++o) {
            float tmp = 0.f;
            #pragma unroll
            for (int i = 0; i < 9; ++i) tmp += s[i] * wd[o * 9 + i];
            acc[o] += tmp;
        }
    }
    #pragma unroll
    for (int i = 0; i < 27; ++i) acc[i] += bdep[g * 27 + i];
    float r2 = rate2p[0];
    const float* wstg = wst + g * 1736;
    float* ob = out + ((size_t)(n * HW_ + hw) * B_ + b) * C_ + g * 64;
    #pragma unroll 1
    for (int o4 = 0; o4 < 16; ++o4) {
        float res[4];
        #pragma unroll
        for (int qq = 0; qq < 4; ++qq) {
            int o = o4 * 4 + qq;
            float a = bst[g * 64 + o];
            #pragma unroll
            for (int i = 0; i < 27; ++i) a += acc[i] * wstg[o * 27 + i];
            res[qq] = r2 * a;
        }
        ((float4*)ob)[o4] = make_float4(res[0], res[1], res[2], res[3]);
    }
}

// ============================================================
// K5: 2D deformable attention -> a2 (post W_out2d), HWC [bn][hw][32]
// ============================================================
__global__ __launch_bounds__(256) void k_attn2d(const float* __restrict__ qkv,
        const float* __restrict__ v2,
        const float* __restrict__ Woff, const float* __restrict__ boff,
        const float* __restrict__ Watt, const float* __restrict__ batt,
        const float* __restrict__ Wout, const float* __restrict__ bout,
        float* __restrict__ a2) {
    int P = blockIdx.x * 256 + threadIdx.x;      // b*NQ + nq
    int b = P / NQ_, nq = P % NQ_;
    int n = nq / HW_, hw = nq % HW_;
    int h = hw / W_, w = hw % W_;
    int bn = b * NIMG_ + n;
    float q[32];
    const float4* qp = (const float4*)(qkv + (size_t)P * 64);
    #pragma unroll
    for (int i = 0; i < 8; ++i) ((float4*)q)[i] = qp[i];
    const float* vbase = v2 + (size_t)bn * HW_ * 32;
    float a2v[32];
    #pragma unroll
    for (int i = 0; i < 32; ++i) a2v[i] = 0.f;
    for (int nh = 0; nh < 8; ++nh) {
        float t0 = batt[nh * 4 + 0], t1 = batt[nh * 4 + 1];
        float t2 = batt[nh * 4 + 2], t3 = batt[nh * 4 + 3];
        for (int c = 0; c < 32; ++c) {
            float qc = q[c];
            const float* wr = Watt + c * 32 + nh * 4;
            t0 += qc * wr[0]; t1 += qc * wr[1]; t2 += qc * wr[2]; t3 += qc * wr[3];
        }
        float m = fmaxf(fmaxf(t0, t1), fmaxf(t2, t3));
        float e0 = expf(t0 - m), e1 = expf(t1 - m), e2 = expf(t2 - m), e3 = expf(t3 - m);
        float inv = 1.f / (e0 + e1 + e2 + e3);
        float pk[4] = {e0 * inv, e1 * inv, e2 * inv, e3 * inv};
        #pragma unroll
        for (int kk = 0; kk < 4; ++kk) {
            int j0 = nh * 8 + kk * 2;
            float ox = boff[j0], oy = boff[j0 + 1];
            for (int c = 0; c < 32; ++c) {
                float qc = q[c];
                ox += qc * Woff[c * 64 + j0];
                oy += qc * Woff[c * 64 + j0 + 1];
            }
            float ppx = (float)w + ox * (79.f / 80.f);
            float ppy = (float)h + oy * (79.f / 80.f);
            float x0 = floorf(ppx), y0 = floorf(ppy);
            float wx = ppx - x0, wy = ppy - y0;
            float s0 = 0.f, s1 = 0.f, s2 = 0.f, s3 = 0.f;
            #pragma unroll
            for (int cy = 0; cy < 2; ++cy) {
                float yf = y0 + (float)cy;
                if (yf < 0.f || yf > 79.f) continue;
                float wyf = cy ? wy : 1.f - wy;
                int yi = (int)yf;
                #pragma unroll
                for (int cx = 0; cx < 2; ++cx) {
                    float xf = x0 + (float)cx;
                    if (xf < 0.f || xf > 79.f) continue;
                    float wgt = wyf * (cx ? wx : 1.f - wx);
                    int xi = (int)xf;
                    float4 vv = *(const float4*)(vbase + ((size_t)yi * W_ + xi) * 32 + nh * 4);
                    s0 += wgt * vv.x; s1 += wgt * vv.y; s2 += wgt * vv.z; s3 += wgt * vv.w;
                }
            }
            float p = pk[kk];
            a2v[nh * 4 + 0] += p * s0; a2v[nh * 4 + 1] += p * s1;
            a2v[nh * 4 + 2] += p * s2; a2v[nh * 4 + 3] += p * s3;
        }
    }
    float ro[32];
    #pragma unroll
    for (int o = 0; o < 32; ++o) ro[o] = bout[o];
    for (int c = 0; c < 32; ++c) {
        float ac = a2v[c];
        const float* wr = Wout + c * 32;
        #pragma unroll
        for (int o = 0; o < 32; ++o) ro[o] += ac * wr[o];
    }
    float* op = a2 + ((size_t)bn * HW_ + hw) * 32;
    #pragma unroll
    for (int i = 0; i < 8; ++i) ((float4*)op)[i] = ((float4*)ro)[i];
}

// ============================================================
// K6: q3/kf/vf = 32->32 projections of x3 (frame-concat bug: src = n==0?0:n-1)
// ============================================================
__global__ __launch_bounds__(256) void k_qkv3(const float* __restrict__ a2,
        const float* __restrict__ Wq3, const float* __restrict__ bq3,
        const float* __restrict__ Wk3, const float* __restrict__ bk3,
        const float* __restrict__ Wv3, const float* __restrict__ bv3,
        float* __restrict__ q3, float* __restrict__ kf, float* __restrict__ vf) {
    int idx = blockIdx.x * 256 + threadIdx.x;    // (b*4+n)*HW + hw
    int bn = idx / HW_, hw = idx % HW_;
    int b = bn >> 2, n = bn & 3;
    int ns = (n == 0) ? 0 : n - 1;
    const float* src = a2 + ((size_t)(b * 4 + ns) * HW_ + hw) * 32;
    float v[32];
    #pragma unroll
    for (int i = 0; i < 8; ++i) ((float4*)v)[i] = ((const float4*)src)[i];
    float oq[32], ok[32], ov[32];
    #pragma unroll
    for (int o = 0; o < 32; ++o) {
        float aq = bq3[o], ak = bk3[o], av = bv3[o];
        #pragma unroll
        for (int c = 0; c < 32; ++c) {
            aq += Wq3[o * 32 + c] * v[c];
            ak += Wk3[o * 32 + c] * v[c];
            av += Wv3[o * 32 + c] * v[c];
        }
        oq[o] = aq; ok[o] = ak; ov[o] = av;
    }
    float* qo = q3 + (size_t)idx * 32;
    float* ko = kf + (size_t)idx * 32;
    float* vo = vf + (size_t)idx * 32;
    #pragma unroll
    for (int i = 0; i < 8; ++i) {
        ((float4*)qo)[i] = ((float4*)oq)[i];
        ((float4*)ko)[i] = ((float4*)ok)[i];
        ((float4*)vo)[i] = ((float4*)ov)[i];
    }
}

// ============================================================
// K7: strided conv3d (W_offA) + gelu + W_offB + tanh*OSC -> sample coords
// ============================================================
__global__ __launch_bounds__(256) void k_offs3d(const float* __restrict__ q3,
        const float* __restrict__ WoffA, const float* __restrict__ boffA,
        const float* __restrict__ WoffB, const float* __restrict__ boffB,
        float* __restrict__ coords) {
    __shared__ float red[4][128];
    __shared__ float hidl[128];
    int t = threadIdx.x;
    int blk = blockIdx.x;                       // zo*100+ho*10+wo
    int zo = blk / 100, r = blk % 100, ho = r / 10, wo = r % 10;
    float acc[4][32];
    #pragma unroll
    for (int b = 0; b < 4; ++b)
        #pragma unroll
        for (int o = 0; o < 32; ++o) acc[b][o] = 0.f;
    for (int tap = t; tap < 400; tap += 256) {
        int kz = tap / 100, r2 = tap % 100, ky = r2 / 10, kx = r2 % 10;
        int zi = zo * 2 + kz - 1, hi = ho * 8 + ky - 1, wi = wo * 8 + kx - 1;
        if (zi < 0 || zi >= NIMG_ || hi < 0 || hi >= H_ || wi < 0 || wi >= W_) continue;
        const float* wb = WoffA + tap;
        int sp = hi * W_ + wi;
        for (int c = 0; c < 32; ++c) {
            float vb[4];
            #pragma unroll
            for (int b = 0; b < 4; ++b)
                vb[b] = q3[((size_t)(b * 4 + zi) * HW_ + sp) * 32 + c];
            #pragma unroll
            for (int o = 0; o < 32; ++o) {
                float wv = wb[(o * 32 + c) * 400];
                #pragma unroll
                for (int b = 0; b < 4; ++b) acc[b][o] += vb[b] * wv;
            }
        }
    }
    #pragma unroll
    for (int b = 0; b < 4; ++b)
        #pragma unroll
        for (int o = 0; o < 32; ++o)
            for (int sh = 32; sh >= 1; sh >>= 1)
                acc[b][o] += __shfl_xor(acc[b][o], sh);
    int lane = t & 63, wv = t >> 6;
    if (lane == 0)
        for (int b = 0; b < 4; ++b)
            for (int o = 0; o < 32; ++o) red[wv][b * 32 + o] = acc[b][o];
    __syncthreads();
    if (t < 128) {
        float v = red[0][t] + red[1][t] + red[2][t] + red[3][t] + boffA[t & 31];
        float v3 = v * v * v;
        hidl[t] = 0.5f * v * (1.f + tanhf(0.7978845608028654f * (v + 0.044715f * v3)));
    }
    __syncthreads();
    if (t < 12) {
        int b = t / 3, j = t % 3;
        float a = boffB[j];
        for (int o = 0; o < 32; ++o) a += WoffB[j * 32 + o] * hidl[b * 32 + o];
        float osc = (j == 0) ? 2.f : 8.f;
        float base = (j == 0) ? (zo * 2 + 0.5f) : ((j == 1) ? (ho * 8 + 3.5f) : (wo * 8 + 3.5f));
        coords[((size_t)b * L3_ + blk) * 3 + j] = base + tanhf(a) * osc;
    }
}

// ============================================================
// K8: trilinear sample kf/vf at coords -> ks/vs [b][200][32]
// ============================================================
__global__ __launch_bounds__(256) void k_trisample(const float* __restrict__ kf,
        const float* __restrict__ vf, const float* __restrict__ coords,
        float* __restrict__ ks, float* __restrict__ vs) {
    int t = threadIdx.x;
    int wv = blockIdx.x * 4 + (t >> 6);          // 0..799
    int b = wv / L3_, l = wv % L3_;
    int lane = t & 63;
    int c = lane & 31;
    const float* src = (lane < 32) ? kf : vf;
    float* dst = (lane < 32) ? ks : vs;
    const float* cp = coords + ((size_t)b * L3_ + l) * 3;
    float cz = cp[0], cy = cp[1], cx = cp[2];
    float z0 = floorf(cz), y0 = floorf(cy), x0 = floorf(cx);
    float wz = cz - z0, wy = cy - y0, wx = cx - x0;
    float acc = 0.f;
    #pragma unroll
    for (int dz = 0; dz < 2; ++dz) {
        float zf = z0 + (float)dz;
        if (zf < 0.f || zf > 3.f) continue;
        float wzf = dz ? wz : 1.f - wz;
        int zi = (int)zf;
        #pragma unroll
        for (int dy = 0; dy < 2; ++dy) {
            float yf = y0 + (float)dy;
            if (yf < 0.f || yf > 79.f) continue;
            float wyf = wzf * (dy ? wy : 1.f - wy);
            int yi = (int)yf;
            #pragma unroll
            for (int dx = 0; dx < 2; ++dx) {
                float xf = x0 + (float)dx;
                if (xf < 0.f || xf > 79.f) continue;
                float wgt = wyf * (dx ? wx : 1.f - wx);
                int xi = (int)xf;
                acc += wgt * src[((size_t)(b * 4 + zi) * HW_ + yi * W_ + xi) * 32 + c];
            }
        }
    }
    dst[((size_t)b * L3_ + l) * 32 + c] = acc;
}

// ============================================================
// K9: 25600-query x 200-key attention per batch -> o3 [b][N][32]
// ============================================================
__global__ __launch_bounds__(256) void k_attn3d(const float* __restrict__ q3,
        const float* __restrict__ ks, const float* __restrict__ vs,
        float* __restrict__ o3) {
    __shared__ __align__(16) float ksl[L3_ * 32];
    __shared__ __align__(16) float vsl[L3_ * 32];
    int t = threadIdx.x;
    int b = blockIdx.x / 100;
    int chunk = blockIdx.x % 100;
    const float4* ksg = (const float4*)(ks + (size_t)b * L3_ * 32);
    const float4* vsg = (const float4*)(vs + (size_t)b * L3_ * 32);
    for (int d = t; d < L3_ * 8; d += 256) {
        ((float4*)ksl)[d] = ksg[d];
        ((float4*)vsl)[d] = vsg[d];
    }
    __syncthreads();
    int N = chunk * 256 + t;
    float q[32];
    const float4* qp = (const float4*)(q3 + ((size_t)b * NQ_ + N) * 32);
    #pragma unroll
    for (int i = 0; i < 8; ++i) ((float4*)q)[i] = qp[i];
    const float scale = 0.17677669529663687f;    // 32^-0.5
    float m = -1e30f;
    for (int l = 0; l < L3_; ++l) {
        const float4* kp = (const float4*)(ksl + l * 32);
        float s = 0.f;
        #pragma unroll
        for (int c4 = 0; c4 < 8; ++c4) {
            float4 kv = kp[c4];
            s += q[c4 * 4 + 0] * kv.x + q[c4 * 4 + 1] * kv.y + q[c4 * 4 + 2] * kv.z + q[c4 * 4 + 3] * kv.w;
        }
        m = fmaxf(m, s);
    }
    m *= scale;
    float den = 0.f;
    float o[32];
    #pragma unroll
    for (int c = 0; c < 32; ++c) o[c] = 0.f;
    for (int l = 0; l < L3_; ++l) {
        const float4* kp = (const float4*)(ksl + l * 32);
        float s = 0.f;
        #pragma unroll
        for (int c4 = 0; c4 < 8; ++c4) {
            float4 kv = kp[c4];
            s += q[c4 * 4 + 0] * kv.x + q[c4 * 4 + 1] * kv.y + q[c4 * 4 + 2] * kv.z + q[c4 * 4 + 3] * kv.w;
        }
        float p = expf(s * scale - m);
        den += p;
        const float4* vp = (const float4*)(vsl + l * 32);
        #pragma unroll
        for (int c4 = 0; c4 < 8; ++c4) {
            float4 vv = vp[c4];
            o[c4 * 4 + 0] += p * vv.x; o[c4 * 4 + 1] += p * vv.y;
            o[c4 * 4 + 2] += p * vv.z; o[c4 * 4 + 3] += p * vv.w;
        }
    }
    float inv = 1.f / den;
    float* op = o3 + ((size_t)b * NQ_ + N) * 32;
    #pragma unroll
    for (int c = 0; c < 32; ++c) op[c] = o[c] * inv;
}

// ============================================================
// K10: out += rate1 * (W_out3 @ o3 + b_out3)
// ============================================================
__global__ __launch_bounds__(256) void k_final(const float* __restrict__ o3,
        const float* __restrict__ W, const float* __restrict__ bias,
        const float* __restrict__ r1p, float* __restrict__ out) {
    int blk = blockIdx.x, t = threadIdx.x;       // blk = N*4 + b
    int b = blk & 3, N = blk >> 2;
    const float4* ovp = (const float4*)(o3 + ((size_t)b * NQ_ + N) * 32);
    float v[32];
    #pragma unroll
    for (int i = 0; i < 8; ++i) ((float4*)v)[i] = ovp[i];
    float a = bias[t];
    const float* wr = W + t * 32;
    #pragma unroll
    for (int c = 0; c < 32; ++c) a += v[c] * wr[c];
    size_t oi = (size_t)blk * 256 + t;
    out[oi] = r1p[0] * a + out[oi];
}

// ============================================================
extern "C" void kernel_launch(void* const* d_in, const int* in_sizes, int n_in,
                              void* d_out, int out_size, void* d_ws, size_t ws_size,
                              hipStream_t stream) {
    (void)in_sizes; (void)n_in; (void)out_size; (void)ws_size;
    const float* x      = (const float*)d_in[0];
    const float* W_qkv  = (const float*)d_in[1];
    const float* b_qkv  = (const float*)d_in[2];
    const float* W_fc   = (const float*)d_in[3];
    const float* b_fc   = (const float*)d_in[4];
    const float* W_doff = (const float*)d_in[5];
    const float* b_doff = (const float*)d_in[6];
    const float* W_dep  = (const float*)d_in[7];
    const float* b_dep  = (const float*)d_in[8];
    const float* W_st   = (const float*)d_in[9];
    const float* b_st   = (const float*)d_in[10];
    const float* W_off2d= (const float*)d_in[11];
    const float* b_off2d= (const float*)d_in[12];
    const float* W_attw = (const float*)d_in[13];
    const float* b_attw = (const float*)d_in[14];
    const float* W_val  = (const float*)d_in[15];
    const float* b_val  = (const float*)d_in[16];
    const float* W_out2d= (const float*)d_in[17];
    const float* b_out2d= (const float*)d_in[18];
    const float* W_q3   = (const float*)d_in[19];
    const float* b_q3   = (const float*)d_in[20];
    const float* W_k3   = (const float*)d_in[21];
    const float* b_k3   = (const float*)d_in[22];
    const float* W_v3   = (const float*)d_in[23];
    const float* b_v3   = (const float*)d_in[24];
    const float* W_offA = (const float*)d_in[25];
    const float* b_offA = (const float*)d_in[26];
    const float* W_offB = (const float*)d_in[27];
    const float* b_offB = (const float*)d_in[28];
    const float* W_out3 = (const float*)d_in[29];
    const float* b_out3 = (const float*)d_in[30];
    const float* rate1  = (const float*)d_in[31];
    const float* rate2  = (const float*)d_in[32];

    float* ws  = (float*)d_ws;
    float* out = (float*)d_out;
    float* qkv = ws + WS_QKV;
    float* fin = ws + WS_FIN;
    float* off = ws + WS_OFF;
    float* v2  = ws + WS_V2;
    float* a2  = ws + WS_A2;
    float* q3  = ws + WS_Q3;
    float* kf  = ws + WS_KF;
    float* vf  = ws + WS_VF;
    float* crd = ws + WS_CRD;
    float* ks  = ws + WS_KS;
    float* vs  = ws + WS_VS;
    float* o3w = ws + WS_O3;

    k_qkv      <<<3200,   256, 0, stream>>>(x, W_qkv, b_qkv, qkv);
    k_fin_v2   <<<400,    256, 0, stream>>>(qkv, W_fc, b_fc, W_val, b_val, fin, v2);
    k_offconv  <<<400,    256, 0, stream>>>(fin, W_doff, b_doff, off);
    k_depst    <<<1600,   256, 0, stream>>>(fin, off, W_dep, b_dep, W_st, b_st, rate2, out);
    k_attn2d   <<<400,    256, 0, stream>>>(qkv, v2, W_off2d, b_off2d, W_attw, b_attw, W_out2d, b_out2d, a2);
    k_qkv3     <<<400,    256, 0, stream>>>(a2, W_q3, b_q3, W_k3, b_k3, W_v3, b_v3, q3, kf, vf);
    k_offs3d   <<<200,    256, 0, stream>>>(q3, W_offA, b_offA, W_offB, b_offB, crd);
    k_trisample<<<200,    256, 0, stream>>>(kf, vf, crd, ks, vs);
    k_attn3d   <<<400,    256, 0, stream>>>(q3, ks, vs, o3w);
    k_final    <<<102400, 256, 0, stream>>>(o3w, W_out3, b_out3, rate1, out);
}

// Round 3
// 1074.754 us; speedup vs baseline: 2.9078x; 1.2101x over previous
//
#include <hip/hip_runtime.h>
#include <math.h>

// ---- problem constants ----
#define B_     4
#define NIMG_  4
#define H_     80
#define W_     80
#define C_     256
#define NH_    8
#define HW_    6400     // H*W
#define NQ_    25600    // NIMG*H*W
#define NPIX_  102400   // B*NQ
#define L3_    200      // 2*10*10 sample points

// ---- workspace layout (float offsets), regions reused across stages ----
#define WS_QKV 0u         // 6,553,600 floats  -> later: q3 @0, kf @3,276,800
#define WS_Q3  0u
#define WS_KF  3276800u
#define WS_FIN 6553600u   // 3,686,400 -> later a2 (3,276,800) -> o3
#define WS_A2  6553600u
#define WS_O3  6553600u
#define WS_OFF 10240000u  // 1,843,200 -> later coords/ks/vs
#define WS_CRD 10240000u
#define WS_KS  10242400u
#define WS_VS  10268000u
#define WS_V2  12083200u  // 3,276,800 -> later vf
#define WS_VF  12083200u
// total = 15,360,000 floats = 61.44 MB

// ============================================================
// K1: qkv = xb @ W_qkv + b_qkv   (rows = b*NQ + n, 64 outputs)
// ============================================================
__global__ __launch_bounds__(256) void k_qkv(const float* __restrict__ x,
        const float* __restrict__ Wq, const float* __restrict__ bq,
        float* __restrict__ qkv) {
    __shared__ __align__(16) float xs[32][256];   // 32 rows staged
    int t = threadIdx.x;
    int row0 = blockIdx.x * 32;
    // cooperative load of 32 rows (x layout: [n][b][c])
    for (int it = 0; it < 8; ++it) {
        int idx = t + it * 256;          // 0..2047 = row(32) * f4(64)
        int r = idx >> 6;
        int f4 = idx & 63;
        int row = row0 + r;
        int b = row / NQ_, n = row % NQ_;
        const float4* src = (const float4*)(x + ((size_t)n * B_ + b) * C_);
        ((float4*)&xs[r][0])[f4] = src[f4];
    }
    __syncthreads();
    int j = t & 63;
    int rbase = (t >> 6) * 8;            // 8 rows per thread
    float acc[8];
    #pragma unroll
    for (int r = 0; r < 8; ++r) acc[r] = 0.f;
    for (int c4 = 0; c4 < 64; ++c4) {
        float w0 = Wq[(c4 * 4 + 0) * 64 + j];
        float w1 = Wq[(c4 * 4 + 1) * 64 + j];
        float w2 = Wq[(c4 * 4 + 2) * 64 + j];
        float w3 = Wq[(c4 * 4 + 3) * 64 + j];
        #pragma unroll
        for (int r = 0; r < 8; ++r) {
            float4 xv = ((const float4*)&xs[rbase + r][0])[c4];
            acc[r] += xv.x * w0 + xv.y * w1 + xv.z * w2 + xv.w * w3;
        }
    }
    float bias = bq[j];
    #pragma unroll
    for (int r = 0; r < 8; ++r) {
        int row = row0 + rbase + r;
        qkv[(size_t)row * 64 + j] = acc[r] + bias;
    }
}

// ============================================================
// K2: fin (36ch, HWC) + v2 (32ch, HWC) per pixel
// ============================================================
__global__ __launch_bounds__(256) void k_fin_v2(const float* __restrict__ qkv,
        const float* __restrict__ Wfc, const float* __restrict__ bfc,
        const float* __restrict__ Wval, const float* __restrict__ bval,
        float* __restrict__ fin, float* __restrict__ v2) {
    int P = blockIdx.x * 256 + threadIdx.x;      // b*NQ + nq
    int b = P / NQ_, nq = P % NQ_;
    int n = nq / HW_, hw = nq % HW_;
    int bn = b * NIMG_ + n;
    float q[64];
    const float4* qp = (const float4*)(qkv + (size_t)P * 64);
    #pragma unroll
    for (int i = 0; i < 16; ++i) ((float4*)q)[i] = qp[i];
    // fin
    float fo[36];
    #pragma unroll
    for (int k = 0; k < 4; ++k)
        #pragma unroll
        for (int o = 0; o < 9; ++o) fo[k * 9 + o] = bfc[o];
    for (int c = 0; c < 16; ++c) {
        #pragma unroll
        for (int o = 0; o < 9; ++o) {
            float wv = Wfc[o * 16 + c];
            #pragma unroll
            for (int k = 0; k < 4; ++k) fo[k * 9 + o] += wv * q[c * 4 + k];
        }
    }
    float* fp = fin + ((size_t)bn * HW_ + hw) * 36;
    #pragma unroll
    for (int i = 0; i < 9; ++i) ((float4*)fp)[i] = ((float4*)fo)[i];
    // v2
    float vo[32];
    #pragma unroll
    for (int j = 0; j < 32; ++j) vo[j] = bval[j];
    for (int c = 0; c < 32; ++c) {
        float qc = q[32 + c];
        #pragma unroll
        for (int j = 0; j < 32; ++j) vo[j] += qc * Wval[c * 32 + j];
    }
    float* vp = v2 + ((size_t)bn * HW_ + hw) * 32;
    #pragma unroll
    for (int i = 0; i < 8; ++i) ((float4*)vp)[i] = ((float4*)vo)[i];
}

// ============================================================
// K3: off = conv2d(fin, W_doff, pad 1) + b_doff  -> HWC [bn][h][w][18]
// ============================================================
__global__ __launch_bounds__(256) void k_offconv(const float* __restrict__ fin,
        const float* __restrict__ Wdoff, const float* __restrict__ bdoff,
        float* __restrict__ off) {
    __shared__ float Wl[5832];  // reorder [tap][c][o]
    int t = threadIdx.x;
    for (int d = t; d < 5832; d += 256) {
        int tap = d / 648, r = d % 648, c = r / 18, o = r % 18;
        Wl[d] = Wdoff[(o * 36 + c) * 9 + tap];
    }
    __syncthreads();
    int P = blockIdx.x * 256 + t;                // bn*HW + hw
    int bn = P / HW_, hw = P % HW_;
    int h = hw / W_, w = hw % W_;
    float acc[18];
    #pragma unroll
    for (int o = 0; o < 18; ++o) acc[o] = bdoff[o];
    for (int ky = 0; ky < 3; ++ky) {
        int hh = h + ky - 1;
        if (hh < 0 || hh >= H_) continue;
        for (int kx = 0; kx < 3; ++kx) {
            int ww = w + kx - 1;
            if (ww < 0 || ww >= W_) continue;
            const float* base = fin + ((size_t)bn * HW_ + hh * W_ + ww) * 36;
            const float* wl = Wl + (ky * 3 + kx) * 648;
            #pragma unroll
            for (int c4 = 0; c4 < 9; ++c4) {
                float4 v = ((const float4*)base)[c4];
                const float* w0 = wl + (c4 * 4) * 18;
                #pragma unroll
                for (int o = 0; o < 18; ++o)
                    acc[o] += v.x * w0[o] + v.y * w0[18 + o] + v.z * w0[36 + o] + v.w * w0[54 + o];
            }
        }
    }
    float* op = off + (size_t)P * 18;
    #pragma unroll
    for (int o = 0; o < 18; ++o) op[o] = acc[o];
}

// ============================================================
// K4: fused 9-tap bilinear gather + grouped dep einsum + st proj
// ============================================================
__global__ __launch_bounds__(256, 4) void k_depst(const float* __restrict__ fin,
        const float* __restrict__ off, const float* __restrict__ Wdep,
        const float* __restrict__ bdep, const float* __restrict__ Wst,
        const float* __restrict__ bst, const float* __restrict__ rate2p,
        float* __restrict__ out) {
    __shared__ float wdepL[8748];       // [((g*9+k)*27+o)*9+i]
    __shared__ float wst[4 * 1736];     // padded per-g stride (1736 mod 32 = 8)
    int t = threadIdx.x;
    for (int d = t; d < 8748; d += 256) {
        int i = d % 9, o = (d / 9) % 27, k = (d / 243) % 9, g = d / 2187;
        wdepL[d] = Wdep[(size_t)(g * 27 + o) * 81 + i * 9 + k];
    }
    for (int d = t; d < 6912; d += 256) {
        int g = d / 1728, r = d % 1728;
        wst[g * 1736 + r] = Wst[d];
    }
    __syncthreads();
    int T = blockIdx.x * 256 + t;
    int P = T >> 2, g = T & 3;
    int bn = P / HW_, hw = P % HW_;
    int h = hw / W_, w = hw % W_;
    int b = bn >> 2, n = bn & 3;
    float offs[18];
    const float* offp = off + (size_t)P * 18;
    #pragma unroll
    for (int i = 0; i < 18; ++i) offs[i] = offp[i];
    const float* finb = fin + (size_t)bn * HW_ * 36 + g * 9;
    float acc[27];
    #pragma unroll
    for (int o = 0; o < 27; ++o) acc[o] = 0.f;
    #pragma unroll 1
    for (int k = 0; k < 9; ++k) {
        float py = (float)h + (float)(k / 3 - 1) + offs[k * 2 + 0];
        float px = (float)w + (float)(k % 3 - 1) + offs[k * 2 + 1];
        float y0 = floorf(py), x0 = floorf(px);
        float wy = py - y0, wx = px - x0;
        float s[9];
        #pragma unroll
        for (int i = 0; i < 9; ++i) s[i] = 0.f;
        #pragma unroll 1
        for (int cy = 0; cy < 2; ++cy) {
            float yf = y0 + (float)cy;
            if (yf < 0.f || yf > 79.f) continue;
            float wyf = cy ? wy : 1.f - wy;
            int yi = (int)yf;
            #pragma unroll 1
            for (int cx = 0; cx < 2; ++cx) {
                float xf = x0 + (float)cx;
                if (xf < 0.f || xf > 79.f) continue;
                float wgt = wyf * (cx ? wx : 1.f - wx);
                int xi = (int)xf;
                const float* cp = finb + ((size_t)yi * W_ + xi) * 36;
                #pragma unroll
                for (int i = 0; i < 9; ++i) s[i] += wgt * cp[i];
            }
        }
        const float* wd = wdepL + (g * 9 + k) * 243;
        #pragma unroll
        for (int o = 0; o < 27; ++o) {
            float tmp = 0.f;
            #pragma unroll
            for (int i = 0; i < 9; ++i) tmp += s[i] * wd[o * 9 + i];
            acc[o] += tmp;
        }
    }
    #pragma unroll
    for (int i = 0; i < 27; ++i) acc[i] += bdep[g * 27 + i];
    float r2 = rate2p[0];
    const float* wstg = wst + g * 1736;
    float* ob = out + ((size_t)(n * HW_ + hw) * B_ + b) * C_ + g * 64;
    #pragma unroll 1
    for (int o4 = 0; o4 < 16; ++o4) {
        float res[4];
        #pragma unroll
        for (int qq = 0; qq < 4; ++qq) {
            int o = o4 * 4 + qq;
            float a = bst[g * 64 + o];
            #pragma unroll
            for (int i = 0; i < 27; ++i) a += acc[i] * wstg[o * 27 + i];
            res[qq] = r2 * a;
        }
        ((float4*)ob)[o4] = make_float4(res[0], res[1], res[2], res[3]);
    }
}

// ============================================================
// K5: 2D deformable attention -> a2 (post W_out2d), HWC [bn][hw][32]
// ============================================================
__global__ __launch_bounds__(256) void k_attn2d(const float* __restrict__ qkv,
        const float* __restrict__ v2,
        const float* __restrict__ Woff, const float* __restrict__ boff,
        const float* __restrict__ Watt, const float* __restrict__ batt,
        const float* __restrict__ Wout, const float* __restrict__ bout,
        float* __restrict__ a2) {
    int P = blockIdx.x * 256 + threadIdx.x;      // b*NQ + nq
    int b = P / NQ_, nq = P % NQ_;
    int n = nq / HW_, hw = nq % HW_;
    int h = hw / W_, w = hw % W_;
    int bn = b * NIMG_ + n;
    float q[32];
    const float4* qp = (const float4*)(qkv + (size_t)P * 64);
    #pragma unroll
    for (int i = 0; i < 8; ++i) ((float4*)q)[i] = qp[i];
    const float* vbase = v2 + (size_t)bn * HW_ * 32;
    float a2v[32];
    #pragma unroll
    for (int i = 0; i < 32; ++i) a2v[i] = 0.f;
    for (int nh = 0; nh < 8; ++nh) {
        float t0 = batt[nh * 4 + 0], t1 = batt[nh * 4 + 1];
        float t2 = batt[nh * 4 + 2], t3 = batt[nh * 4 + 3];
        for (int c = 0; c < 32; ++c) {
            float qc = q[c];
            const float* wr = Watt + c * 32 + nh * 4;
            t0 += qc * wr[0]; t1 += qc * wr[1]; t2 += qc * wr[2]; t3 += qc * wr[3];
        }
        float m = fmaxf(fmaxf(t0, t1), fmaxf(t2, t3));
        float e0 = expf(t0 - m), e1 = expf(t1 - m), e2 = expf(t2 - m), e3 = expf(t3 - m);
        float inv = 1.f / (e0 + e1 + e2 + e3);
        float pk[4] = {e0 * inv, e1 * inv, e2 * inv, e3 * inv};
        #pragma unroll
        for (int kk = 0; kk < 4; ++kk) {
            int j0 = nh * 8 + kk * 2;
            float ox = boff[j0], oy = boff[j0 + 1];
            for (int c = 0; c < 32; ++c) {
                float qc = q[c];
                ox += qc * Woff[c * 64 + j0];
                oy += qc * Woff[c * 64 + j0 + 1];
            }
            float ppx = (float)w + ox * (79.f / 80.f);
            float ppy = (float)h + oy * (79.f / 80.f);
            float x0 = floorf(ppx), y0 = floorf(ppy);
            float wx = ppx - x0, wy = ppy - y0;
            float s0 = 0.f, s1 = 0.f, s2 = 0.f, s3 = 0.f;
            #pragma unroll
            for (int cy = 0; cy < 2; ++cy) {
                float yf = y0 + (float)cy;
                if (yf < 0.f || yf > 79.f) continue;
                float wyf = cy ? wy : 1.f - wy;
                int yi = (int)yf;
                #pragma unroll
                for (int cx = 0; cx < 2; ++cx) {
                    float xf = x0 + (float)cx;
                    if (xf < 0.f || xf > 79.f) continue;
                    float wgt = wyf * (cx ? wx : 1.f - wx);
                    int xi = (int)xf;
                    float4 vv = *(const float4*)(vbase + ((size_t)yi * W_ + xi) * 32 + nh * 4);
                    s0 += wgt * vv.x; s1 += wgt * vv.y; s2 += wgt * vv.z; s3 += wgt * vv.w;
                }
            }
            float p = pk[kk];
            a2v[nh * 4 + 0] += p * s0; a2v[nh * 4 + 1] += p * s1;
            a2v[nh * 4 + 2] += p * s2; a2v[nh * 4 + 3] += p * s3;
        }
    }
    float ro[32];
    #pragma unroll
    for (int o = 0; o < 32; ++o) ro[o] = bout[o];
    for (int c = 0; c < 32; ++c) {
        float ac = a2v[c];
        const float* wr = Wout + c * 32;
        #pragma unroll
        for (int o = 0; o < 32; ++o) ro[o] += ac * wr[o];
    }
    float* op = a2 + ((size_t)bn * HW_ + hw) * 32;
    #pragma unroll
    for (int i = 0; i < 8; ++i) ((float4*)op)[i] = ((float4*)ro)[i];
}

// ============================================================
// K6: q3/kf/vf = 32->32 projections of x3 (frame-concat bug: src = n==0?0:n-1)
// ============================================================
__global__ __launch_bounds__(256) void k_qkv3(const float* __restrict__ a2,
        const float* __restrict__ Wq3, const float* __restrict__ bq3,
        const float* __restrict__ Wk3, const float* __restrict__ bk3,
        const float* __restrict__ Wv3, const float* __restrict__ bv3,
        float* __restrict__ q3, float* __restrict__ kf, float* __restrict__ vf) {
    int idx = blockIdx.x * 256 + threadIdx.x;    // (b*4+n)*HW + hw
    int bn = idx / HW_, hw = idx % HW_;
    int b = bn >> 2, n = bn & 3;
    int ns = (n == 0) ? 0 : n - 1;
    const float* src = a2 + ((size_t)(b * 4 + ns) * HW_ + hw) * 32;
    float v[32];
    #pragma unroll
    for (int i = 0; i < 8; ++i) ((float4*)v)[i] = ((const float4*)src)[i];
    float oq[32], ok[32], ov[32];
    #pragma unroll
    for (int o = 0; o < 32; ++o) {
        float aq = bq3[o], ak = bk3[o], av = bv3[o];
        #pragma unroll
        for (int c = 0; c < 32; ++c) {
            aq += Wq3[o * 32 + c] * v[c];
            ak += Wk3[o * 32 + c] * v[c];
            av += Wv3[o * 32 + c] * v[c];
        }
        oq[o] = aq; ok[o] = ak; ov[o] = av;
    }
    float* qo = q3 + (size_t)idx * 32;
    float* ko = kf + (size_t)idx * 32;
    float* vo = vf + (size_t)idx * 32;
    #pragma unroll
    for (int i = 0; i < 8; ++i) {
        ((float4*)qo)[i] = ((float4*)oq)[i];
        ((float4*)ko)[i] = ((float4*)ok)[i];
        ((float4*)vo)[i] = ((float4*)ov)[i];
    }
}

// ============================================================
// K7: strided conv3d (W_offA) + gelu + W_offB + tanh*OSC -> sample coords
// ============================================================
__global__ __launch_bounds__(256) void k_offs3d(const float* __restrict__ q3,
        const float* __restrict__ WoffA, const float* __restrict__ boffA,
        const float* __restrict__ WoffB, const float* __restrict__ boffB,
        float* __restrict__ coords) {
    __shared__ float red[4][128];
    __shared__ float hidl[128];
    int t = threadIdx.x;
    int blk = blockIdx.x;                       // zo*100+ho*10+wo
    int zo = blk / 100, r = blk % 100, ho = r / 10, wo = r % 10;
    float acc[4][32];
    #pragma unroll
    for (int b = 0; b < 4; ++b)
        #pragma unroll
        for (int o = 0; o < 32; ++o) acc[b][o] = 0.f;
    for (int tap = t; tap < 400; tap += 256) {
        int kz = tap / 100, r2 = tap % 100, ky = r2 / 10, kx = r2 % 10;
        int zi = zo * 2 + kz - 1, hi = ho * 8 + ky - 1, wi = wo * 8 + kx - 1;
        if (zi < 0 || zi >= NIMG_ || hi < 0 || hi >= H_ || wi < 0 || wi >= W_) continue;
        const float* wb = WoffA + tap;
        int sp = hi * W_ + wi;
        for (int c = 0; c < 32; ++c) {
            float vb[4];
            #pragma unroll
            for (int b = 0; b < 4; ++b)
                vb[b] = q3[((size_t)(b * 4 + zi) * HW_ + sp) * 32 + c];
            #pragma unroll
            for (int o = 0; o < 32; ++o) {
                float wv = wb[(o * 32 + c) * 400];
                #pragma unroll
                for (int b = 0; b < 4; ++b) acc[b][o] += vb[b] * wv;
            }
        }
    }
    #pragma unroll
    for (int b = 0; b < 4; ++b)
        #pragma unroll
        for (int o = 0; o < 32; ++o)
            for (int sh = 32; sh >= 1; sh >>= 1)
                acc[b][o] += __shfl_xor(acc[b][o], sh);
    int lane = t & 63, wv = t >> 6;
    if (lane == 0)
        for (int b = 0; b < 4; ++b)
            for (int o = 0; o < 32; ++o) red[wv][b * 32 + o] = acc[b][o];
    __syncthreads();
    if (t < 128) {
        float v = red[0][t] + red[1][t] + red[2][t] + red[3][t] + boffA[t & 31];
        float v3 = v * v * v;
        hidl[t] = 0.5f * v * (1.f + tanhf(0.7978845608028654f * (v + 0.044715f * v3)));
    }
    __syncthreads();
    if (t < 12) {
        int b = t / 3, j = t % 3;
        float a = boffB[j];
        for (int o = 0; o < 32; ++o) a += WoffB[j * 32 + o] * hidl[b * 32 + o];
        float osc = (j == 0) ? 2.f : 8.f;
        float base = (j == 0) ? (zo * 2 + 0.5f) : ((j == 1) ? (ho * 8 + 3.5f) : (wo * 8 + 3.5f));
        coords[((size_t)b * L3_ + blk) * 3 + j] = base + tanhf(a) * osc;
    }
}

// ============================================================
// K8: trilinear sample kf/vf at coords -> ks/vs [b][200][32]
// ============================================================
__global__ __launch_bounds__(256) void k_trisample(const float* __restrict__ kf,
        const float* __restrict__ vf, const float* __restrict__ coords,
        float* __restrict__ ks, float* __restrict__ vs) {
    int t = threadIdx.x;
    int wv = blockIdx.x * 4 + (t >> 6);          // 0..799
    int b = wv / L3_, l = wv % L3_;
    int lane = t & 63;
    int c = lane & 31;
    const float* src = (lane < 32) ? kf : vf;
    float* dst = (lane < 32) ? ks : vs;
    const float* cp = coords + ((size_t)b * L3_ + l) * 3;
    float cz = cp[0], cy = cp[1], cx = cp[2];
    float z0 = floorf(cz), y0 = floorf(cy), x0 = floorf(cx);
    float wz = cz - z0, wy = cy - y0, wx = cx - x0;
    float acc = 0.f;
    #pragma unroll
    for (int dz = 0; dz < 2; ++dz) {
        float zf = z0 + (float)dz;
        if (zf < 0.f || zf > 3.f) continue;
        float wzf = dz ? wz : 1.f - wz;
        int zi = (int)zf;
        #pragma unroll
        for (int dy = 0; dy < 2; ++dy) {
            float yf = y0 + (float)dy;
            if (yf < 0.f || yf > 79.f) continue;
            float wyf = wzf * (dy ? wy : 1.f - wy);
            int yi = (int)yf;
            #pragma unroll
            for (int dx = 0; dx < 2; ++dx) {
                float xf = x0 + (float)dx;
                if (xf < 0.f || xf > 79.f) continue;
                float wgt = wyf * (dx ? wx : 1.f - wx);
                int xi = (int)xf;
                acc += wgt * src[((size_t)(b * 4 + zi) * HW_ + yi * W_ + xi) * 32 + c];
            }
        }
    }
    dst[((size_t)b * L3_ + l) * 32 + c] = acc;
}

// ============================================================
// K9: 25600-query x 200-key attention per batch -> o3 [b][N][32]
// ============================================================
__global__ __launch_bounds__(256) void k_attn3d(const float* __restrict__ q3,
        const float* __restrict__ ks, const float* __restrict__ vs,
        float* __restrict__ o3) {
    __shared__ __align__(16) float ksl[L3_ * 32];
    __shared__ __align__(16) float vsl[L3_ * 32];
    int t = threadIdx.x;
    int b = blockIdx.x / 100;
    int chunk = blockIdx.x % 100;
    const float4* ksg = (const float4*)(ks + (size_t)b * L3_ * 32);
    const float4* vsg = (const float4*)(vs + (size_t)b * L3_ * 32);
    for (int d = t; d < L3_ * 8; d += 256) {
        ((float4*)ksl)[d] = ksg[d];
        ((float4*)vsl)[d] = vsg[d];
    }
    __syncthreads();
    int N = chunk * 256 + t;
    float q[32];
    const float4* qp = (const float4*)(q3 + ((size_t)b * NQ_ + N) * 32);
    #pragma unroll
    for (int i = 0; i < 8; ++i) ((float4*)q)[i] = qp[i];
    const float scale = 0.17677669529663687f;    // 32^-0.5
    float m = -1e30f;
    for (int l = 0; l < L3_; ++l) {
        const float4* kp = (const float4*)(ksl + l * 32);
        float s = 0.f;
        #pragma unroll
        for (int c4 = 0; c4 < 8; ++c4) {
            float4 kv = kp[c4];
            s += q[c4 * 4 + 0] * kv.x + q[c4 * 4 + 1] * kv.y + q[c4 * 4 + 2] * kv.z + q[c4 * 4 + 3] * kv.w;
        }
        m = fmaxf(m, s);
    }
    m *= scale;
    float den = 0.f;
    float o[32];
    #pragma unroll
    for (int c = 0; c < 32; ++c) o[c] = 0.f;
    for (int l = 0; l < L3_; ++l) {
        const float4* kp = (const float4*)(ksl + l * 32);
        float s = 0.f;
        #pragma unroll
        for (int c4 = 0; c4 < 8; ++c4) {
            float4 kv = kp[c4];
            s += q[c4 * 4 + 0] * kv.x + q[c4 * 4 + 1] * kv.y + q[c4 * 4 + 2] * kv.z + q[c4 * 4 + 3] * kv.w;
        }
        float p = expf(s * scale - m);
        den += p;
        const float4* vp = (const float4*)(vsl + l * 32);
        #pragma unroll
        for (int c4 = 0; c4 < 8; ++c4) {
            float4 vv = vp[c4];
            o[c4 * 4 + 0] += p * vv.x; o[c4 * 4 + 1] += p * vv.y;
            o[c4 * 4 + 2] += p * vv.z; o[c4 * 4 + 3] += p * vv.w;
        }
    }
    float inv = 1.f / den;
    float* op = o3 + ((size_t)b * NQ_ + N) * 32;
    #pragma unroll
    for (int c = 0; c < 32; ++c) op[c] = o[c] * inv;
}

// ============================================================
// K10 (R3): tiled GEMM  out += r1 * (o3 @ W_out3^T + bias)
// 800 blocks x 128 rows x 256 ch; per-thread 8x16 register tile.
// Row R = N*4+b matches out layout; o3 row at (b*NQ+N)*32.
// ============================================================
__global__ __launch_bounds__(256) void k_final(const float* __restrict__ o3,
        const float* __restrict__ W, const float* __restrict__ bias,
        const float* __restrict__ r1p, float* __restrict__ out) {
    __shared__ float o3T[32 * 128];     // [k][row]
    __shared__ float WT[32 * 260];      // [k][c], stride 260 breaks bank aliasing
    int t = threadIdx.x;
    int R0 = blockIdx.x * 128;
    // stage o3: thread t covers row t>>1, k half (t&1)*16 (64B contiguous reads)
    {
        int row = t >> 1, k0 = (t & 1) * 16;
        int R = R0 + row;
        int b = R & 3, N = R >> 2;
        const float* src = o3 + ((size_t)b * NQ_ + N) * 32 + k0;
        #pragma unroll
        for (int j = 0; j < 16; ++j) o3T[(k0 + j) * 128 + row] = src[j];
    }
    // stage W: global [c][k] (coalesced 128B/row) -> LDS [k][c]
    for (int d = t; d < 8192; d += 256) {
        int c = d >> 5, k = d & 31;
        WT[k * 260 + c] = W[d];
    }
    __syncthreads();
    int tc = t & 15;          // channel lane: c = tc + 16*ci (strided -> conflict-free)
    int tr = t >> 4;          // row group: rows r0..r0+7
    int r0 = tr * 8;
    float acc[8][16];
    #pragma unroll
    for (int i = 0; i < 8; ++i)
        #pragma unroll
        for (int j = 0; j < 16; ++j) acc[i][j] = 0.f;
    #pragma unroll 1
    for (int k = 0; k < 32; ++k) {
        float a[8];
        *(float4*)&a[0] = *(const float4*)&o3T[k * 128 + r0];
        *(float4*)&a[4] = *(const float4*)&o3T[k * 128 + r0 + 4];
        float wv[16];
        #pragma unroll
        for (int ci = 0; ci < 16; ++ci) wv[ci] = WT[k * 260 + tc + 16 * ci];
        #pragma unroll
        for (int i = 0; i < 8; ++i)
            #pragma unroll
            for (int j = 0; j < 16; ++j) acc[i][j] += a[i] * wv[j];
    }
    float r1 = r1p[0];
    float bs[16];
    #pragma unroll
    for (int ci = 0; ci < 16; ++ci) bs[ci] = bias[tc + 16 * ci];
    #pragma unroll 1
    for (int i = 0; i < 8; ++i) {
        size_t rowbase = (size_t)(R0 + r0 + i) * 256;
        #pragma unroll
        for (int j = 0; j < 16; ++j) {
            size_t oi = rowbase + tc + 16 * j;
            out[oi] = r1 * (acc[i][j] + bs[j]) + out[oi];
        }
    }
}

// ============================================================
extern "C" void kernel_launch(void* const* d_in, const int* in_sizes, int n_in,
                              void* d_out, int out_size, void* d_ws, size_t ws_size,
                              hipStream_t stream) {
    (void)in_sizes; (void)n_in; (void)out_size; (void)ws_size;
    const float* x      = (const float*)d_in[0];
    const float* W_qkv  = (const float*)d_in[1];
    const float* b_qkv  = (const float*)d_in[2];
    const float* W_fc   = (const float*)d_in[3];
    const float* b_fc   = (const float*)d_in[4];
    const float* W_doff = (const float*)d_in[5];
    const float* b_doff = (const float*)d_in[6];
    const float* W_dep  = (const float*)d_in[7];
    const float* b_dep  = (const float*)d_in[8];
    const float* W_st   = (const float*)d_in[9];
    const float* b_st   = (const float*)d_in[10];
    const float* W_off2d= (const float*)d_in[11];
    const float* b_off2d= (const float*)d_in[12];
    const float* W_attw = (const float*)d_in[13];
    const float* b_attw = (const float*)d_in[14];
    const float* W_val  = (const float*)d_in[15];
    const float* b_val  = (const float*)d_in[16];
    const float* W_out2d= (const float*)d_in[17];
    const float* b_out2d= (const float*)d_in[18];
    const float* W_q3   = (const float*)d_in[19];
    const float* b_q3   = (const float*)d_in[20];
    const float* W_k3   = (const float*)d_in[21];
    const float* b_k3   = (const float*)d_in[22];
    const float* W_v3   = (const float*)d_in[23];
    const float* b_v3   = (const float*)d_in[24];
    const float* W_offA = (const float*)d_in[25];
    const float* b_offA = (const float*)d_in[26];
    const float* W_offB = (const float*)d_in[27];
    const float* b_offB = (const float*)d_in[28];
    const float* W_out3 = (const float*)d_in[29];
    const float* b_out3 = (const float*)d_in[30];
    const float* rate1  = (const float*)d_in[31];
    const float* rate2  = (const float*)d_in[32];

    float* ws  = (float*)d_ws;
    float* out = (float*)d_out;
    float* qkv = ws + WS_QKV;
    float* fin = ws + WS_FIN;
    float* off = ws + WS_OFF;
    float* v2  = ws + WS_V2;
    float* a2  = ws + WS_A2;
    float* q3  = ws + WS_Q3;
    float* kf  = ws + WS_KF;
    float* vf  = ws + WS_VF;
    float* crd = ws + WS_CRD;
    float* ks  = ws + WS_KS;
    float* vs  = ws + WS_VS;
    float* o3w = ws + WS_O3;

    k_qkv      <<<3200,   256, 0, stream>>>(x, W_qkv, b_qkv, qkv);
    k_fin_v2   <<<400,    256, 0, stream>>>(qkv, W_fc, b_fc, W_val, b_val, fin, v2);
    k_offconv  <<<400,    256, 0, stream>>>(fin, W_doff, b_doff, off);
    k_depst    <<<1600,   256, 0, stream>>>(fin, off, W_dep, b_dep, W_st, b_st, rate2, out);
    k_attn2d   <<<400,    256, 0, stream>>>(qkv, v2, W_off2d, b_off2d, W_attw, b_attw, W_out2d, b_out2d, a2);
    k_qkv3     <<<400,    256, 0, stream>>>(a2, W_q3, b_q3, W_k3, b_k3, W_v3, b_v3, q3, kf, vf);
    k_offs3d   <<<200,    256, 0, stream>>>(q3, W_offA, b_offA, W_offB, b_offB, crd);
    k_trisample<<<200,    256, 0, stream>>>(kf, vf, crd, ks, vs);
    k_attn3d   <<<400,    256, 0, stream>>>(q3, ks, vs, o3w);
    k_final    <<<800,    256, 0, stream>>>(o3w, W_out3, b_out3, rate1, out);
}

// Round 4
// 965.296 us; speedup vs baseline: 3.2375x; 1.1134x over previous
//
#include <hip/hip_runtime.h>
#include <math.h>

// ---- problem constants ----
#define B_     4
#define NIMG_  4
#define H_     80
#define W_     80
#define C_     256
#define NH_    8
#define HW_    6400     // H*W
#define NQ_    25600    // NIMG*H*W
#define NPIX_  102400   // B*NQ
#define L3_    200      // 2*10*10 sample points

// ---- workspace layout (float offsets), regions reused across stages ----
#define WS_QKV 0u
#define WS_Q3  0u
#define WS_KF  3276800u
#define WS_FIN 6553600u
#define WS_A2  6553600u
#define WS_O3  6553600u
#define WS_OFF 10240000u
#define WS_CRD 10240000u
#define WS_KS  10242400u
#define WS_VS  10268000u
#define WS_V2  12083200u
#define WS_VF  12083200u
// total = 15,360,000 floats = 61.44 MB

// ============================================================
// K1: qkv = xb @ W_qkv + b_qkv
// ============================================================
__global__ __launch_bounds__(256) void k_qkv(const float* __restrict__ x,
        const float* __restrict__ Wq, const float* __restrict__ bq,
        float* __restrict__ qkv) {
    __shared__ __align__(16) float xs[32][256];
    int t = threadIdx.x;
    int row0 = blockIdx.x * 32;
    for (int it = 0; it < 8; ++it) {
        int idx = t + it * 256;
        int r = idx >> 6;
        int f4 = idx & 63;
        int row = row0 + r;
        int b = row / NQ_, n = row % NQ_;
        const float4* src = (const float4*)(x + ((size_t)n * B_ + b) * C_);
        ((float4*)&xs[r][0])[f4] = src[f4];
    }
    __syncthreads();
    int j = t & 63;
    int rbase = (t >> 6) * 8;
    float acc[8];
    #pragma unroll
    for (int r = 0; r < 8; ++r) acc[r] = 0.f;
    for (int c4 = 0; c4 < 64; ++c4) {
        float w0 = Wq[(c4 * 4 + 0) * 64 + j];
        float w1 = Wq[(c4 * 4 + 1) * 64 + j];
        float w2 = Wq[(c4 * 4 + 2) * 64 + j];
        float w3 = Wq[(c4 * 4 + 3) * 64 + j];
        #pragma unroll
        for (int r = 0; r < 8; ++r) {
            float4 xv = ((const float4*)&xs[rbase + r][0])[c4];
            acc[r] += xv.x * w0 + xv.y * w1 + xv.z * w2 + xv.w * w3;
        }
    }
    float bias = bq[j];
    #pragma unroll
    for (int r = 0; r < 8; ++r) {
        int row = row0 + rbase + r;
        qkv[(size_t)row * 64 + j] = acc[r] + bias;
    }
}

// ============================================================
// K2: fin (36ch, HWC) + v2 (32ch, HWC) per pixel. R4: weights in LDS.
// ============================================================
__global__ __launch_bounds__(256) void k_fin_v2(const float* __restrict__ qkv,
        const float* __restrict__ Wfc, const float* __restrict__ bfc,
        const float* __restrict__ Wval, const float* __restrict__ bval,
        float* __restrict__ fin, float* __restrict__ v2) {
    __shared__ float WvalL[1024], WfcL[144], bfcL[9], bvalL[32];
    int t = threadIdx.x;
    for (int d = t; d < 1024; d += 256) WvalL[d] = Wval[d];
    if (t < 144) WfcL[t] = Wfc[t];
    if (t >= 160 && t < 169) bfcL[t - 160] = bfc[t - 160];
    if (t >= 192 && t < 224) bvalL[t - 192] = bval[t - 192];
    __syncthreads();
    int P = blockIdx.x * 256 + t;
    int b = P / NQ_, nq = P % NQ_;
    int n = nq / HW_, hw = nq % HW_;
    int bn = b * NIMG_ + n;
    float q[64];
    const float4* qp = (const float4*)(qkv + (size_t)P * 64);
    #pragma unroll
    for (int i = 0; i < 16; ++i) ((float4*)q)[i] = qp[i];
    float fo[36];
    #pragma unroll
    for (int k = 0; k < 4; ++k)
        #pragma unroll
        for (int o = 0; o < 9; ++o) fo[k * 9 + o] = bfcL[o];
    for (int c = 0; c < 16; ++c) {
        #pragma unroll
        for (int o = 0; o < 9; ++o) {
            float wv = WfcL[o * 16 + c];
            #pragma unroll
            for (int k = 0; k < 4; ++k) fo[k * 9 + o] += wv * q[c * 4 + k];
        }
    }
    float* fp = fin + ((size_t)bn * HW_ + hw) * 36;
    #pragma unroll
    for (int i = 0; i < 9; ++i) ((float4*)fp)[i] = ((float4*)fo)[i];
    float vo[32];
    #pragma unroll
    for (int j = 0; j < 32; ++j) vo[j] = bvalL[j];
    for (int c = 0; c < 32; ++c) {
        float qc = q[32 + c];
        #pragma unroll
        for (int j = 0; j < 32; ++j) vo[j] += qc * WvalL[c * 32 + j];
    }
    float* vp = v2 + ((size_t)bn * HW_ + hw) * 32;
    #pragma unroll
    for (int i = 0; i < 8; ++i) ((float4*)vp)[i] = ((float4*)vo)[i];
}

// ============================================================
// K3: off = conv2d(fin, W_doff, pad 1) + b_doff  -> HWC [bn][h][w][18]
// ============================================================
__global__ __launch_bounds__(256) void k_offconv(const float* __restrict__ fin,
        const float* __restrict__ Wdoff, const float* __restrict__ bdoff,
        float* __restrict__ off) {
    __shared__ float Wl[5832];  // [tap][c][o]
    int t = threadIdx.x;
    for (int d = t; d < 5832; d += 256) {
        int tap = d / 648, r = d % 648, c = r / 18, o = r % 18;
        Wl[d] = Wdoff[(o * 36 + c) * 9 + tap];
    }
    __syncthreads();
    int P = blockIdx.x * 256 + t;
    int bn = P / HW_, hw = P % HW_;
    int h = hw / W_, w = hw % W_;
    float acc[18];
    #pragma unroll
    for (int o = 0; o < 18; ++o) acc[o] = bdoff[o];
    for (int ky = 0; ky < 3; ++ky) {
        int hh = h + ky - 1;
        if (hh < 0 || hh >= H_) continue;
        for (int kx = 0; kx < 3; ++kx) {
            int ww = w + kx - 1;
            if (ww < 0 || ww >= W_) continue;
            const float* base = fin + ((size_t)bn * HW_ + hh * W_ + ww) * 36;
            const float* wl = Wl + (ky * 3 + kx) * 648;
            #pragma unroll
            for (int c4 = 0; c4 < 9; ++c4) {
                float4 v = ((const float4*)base)[c4];
                const float* w0 = wl + (c4 * 4) * 18;
                #pragma unroll
                for (int o = 0; o < 18; ++o)
                    acc[o] += v.x * w0[o] + v.y * w0[18 + o] + v.z * w0[36 + o] + v.w * w0[54 + o];
            }
        }
    }
    float* op = off + (size_t)P * 18;
    #pragma unroll
    for (int o = 0; o < 18; ++o) op[o] = acc[o];
}

// ============================================================
// K4 (R4): block-uniform g. 256 pixels/block, g = blockIdx & 3.
// LDS = only this g's weights (15.7 KB) -> 5 waves/SIMD occupancy cap.
// Weight LDS reads are wave-uniform broadcasts.
// ============================================================
__global__ __launch_bounds__(256, 5) void k_depst(const float* __restrict__ fin,
        const float* __restrict__ off, const float* __restrict__ Wdep,
        const float* __restrict__ bdep, const float* __restrict__ Wst,
        const float* __restrict__ bst, const float* __restrict__ rate2p,
        float* __restrict__ out) {
    __shared__ float wdepL[2187];       // [(k*27+o)*9+i] for this g
    __shared__ float wstL[1728];        // [o2*27+i] for this g
    int t = threadIdx.x;
    int g = blockIdx.x & 3;
    for (int d = t; d < 2187; d += 256) {
        int i = d % 9, o = (d / 9) % 27, k = d / 243;
        wdepL[d] = Wdep[(size_t)(g * 27 + o) * 81 + i * 9 + k];
    }
    for (int d = t; d < 1728; d += 256) wstL[d] = Wst[g * 1728 + d];
    __syncthreads();
    int P = (blockIdx.x >> 2) * 256 + t;
    int bn = P / HW_, hw = P % HW_;
    int h = hw / W_, w = hw % W_;
    int b = bn >> 2, n = bn & 3;
    float offs[18];
    const float* offp = off + (size_t)P * 18;
    #pragma unroll
    for (int i = 0; i < 18; ++i) offs[i] = offp[i];
    const float* finb = fin + (size_t)bn * HW_ * 36 + g * 9;
    float acc[27];
    #pragma unroll
    for (int o = 0; o < 27; ++o) acc[o] = 0.f;
    #pragma unroll 1
    for (int k = 0; k < 9; ++k) {
        float py = (float)h + (float)(k / 3 - 1) + offs[k * 2 + 0];
        float px = (float)w + (float)(k % 3 - 1) + offs[k * 2 + 1];
        float y0 = floorf(py), x0 = floorf(px);
        float wy = py - y0, wx = px - x0;
        float s[9];
        #pragma unroll
        for (int i = 0; i < 9; ++i) s[i] = 0.f;
        #pragma unroll 1
        for (int cy = 0; cy < 2; ++cy) {
            float yf = y0 + (float)cy;
            if (yf < 0.f || yf > 79.f) continue;
            float wyf = cy ? wy : 1.f - wy;
            int yi = (int)yf;
            #pragma unroll 1
            for (int cx = 0; cx < 2; ++cx) {
                float xf = x0 + (float)cx;
                if (xf < 0.f || xf > 79.f) continue;
                float wgt = wyf * (cx ? wx : 1.f - wx);
                int xi = (int)xf;
                const float* cp = finb + ((size_t)yi * W_ + xi) * 36;
                #pragma unroll
                for (int i = 0; i < 9; ++i) s[i] += wgt * cp[i];
            }
        }
        const float* wd = wdepL + k * 243;
        #pragma unroll
        for (int o = 0; o < 27; ++o) {
            float tmp = 0.f;
            #pragma unroll
            for (int i = 0; i < 9; ++i) tmp += s[i] * wd[o * 9 + i];
            acc[o] += tmp;
        }
    }
    #pragma unroll
    for (int i = 0; i < 27; ++i) acc[i] += bdep[g * 27 + i];
    float r2 = rate2p[0];
    float* ob = out + ((size_t)(n * HW_ + hw) * B_ + b) * C_ + g * 64;
    #pragma unroll 1
    for (int o4 = 0; o4 < 16; ++o4) {
        float res[4];
        #pragma unroll
        for (int qq = 0; qq < 4; ++qq) {
            int o = o4 * 4 + qq;
            float a = bst[g * 64 + o];
            #pragma unroll
            for (int i = 0; i < 27; ++i) a += acc[i] * wstL[o * 27 + i];
            res[qq] = r2 * a;
        }
        ((float4*)ob)[o4] = make_float4(res[0], res[1], res[2], res[3]);
    }
}

// ============================================================
// K5: 2D deformable attention. R4: all weights staged in LDS.
// ============================================================
__global__ __launch_bounds__(256) void k_attn2d(const float* __restrict__ qkv,
        const float* __restrict__ v2,
        const float* __restrict__ Woff, const float* __restrict__ boff,
        const float* __restrict__ Watt, const float* __restrict__ batt,
        const float* __restrict__ Wout, const float* __restrict__ bout,
        float* __restrict__ a2) {
    __shared__ float WoffL[2048], WattL[1024], WoutL[1024];
    __shared__ float boffL[64], battL[32], boutL[32];
    int t = threadIdx.x;
    for (int d = t; d < 2048; d += 256) WoffL[d] = Woff[d];
    for (int d = t; d < 1024; d += 256) { WattL[d] = Watt[d]; WoutL[d] = Wout[d]; }
    if (t < 64) boffL[t] = boff[t];
    else if (t < 96) battL[t - 64] = batt[t - 64];
    else if (t < 128) boutL[t - 96] = bout[t - 96];
    __syncthreads();
    int P = blockIdx.x * 256 + t;
    int b = P / NQ_, nq = P % NQ_;
    int n = nq / HW_, hw = nq % HW_;
    int h = hw / W_, w = hw % W_;
    int bn = b * NIMG_ + n;
    float q[32];
    const float4* qp = (const float4*)(qkv + (size_t)P * 64);
    #pragma unroll
    for (int i = 0; i < 8; ++i) ((float4*)q)[i] = qp[i];
    const float* vbase = v2 + (size_t)bn * HW_ * 32;
    float a2v[32];
    #pragma unroll
    for (int i = 0; i < 32; ++i) a2v[i] = 0.f;
    for (int nh = 0; nh < 8; ++nh) {
        float t0 = battL[nh * 4 + 0], t1 = battL[nh * 4 + 1];
        float t2 = battL[nh * 4 + 2], t3 = battL[nh * 4 + 3];
        for (int c = 0; c < 32; ++c) {
            float qc = q[c];
            const float* wr = WattL + c * 32 + nh * 4;
            t0 += qc * wr[0]; t1 += qc * wr[1]; t2 += qc * wr[2]; t3 += qc * wr[3];
        }
        float m = fmaxf(fmaxf(t0, t1), fmaxf(t2, t3));
        float e0 = expf(t0 - m), e1 = expf(t1 - m), e2 = expf(t2 - m), e3 = expf(t3 - m);
        float inv = 1.f / (e0 + e1 + e2 + e3);
        float pk[4] = {e0 * inv, e1 * inv, e2 * inv, e3 * inv};
        #pragma unroll
        for (int kk = 0; kk < 4; ++kk) {
            int j0 = nh * 8 + kk * 2;
            float ox = boffL[j0], oy = boffL[j0 + 1];
            for (int c = 0; c < 32; ++c) {
                float qc = q[c];
                ox += qc * WoffL[c * 64 + j0];
                oy += qc * WoffL[c * 64 + j0 + 1];
            }
            float ppx = (float)w + ox * (79.f / 80.f);
            float ppy = (float)h + oy * (79.f / 80.f);
            float x0 = floorf(ppx), y0 = floorf(ppy);
            float wx = ppx - x0, wy = ppy - y0;
            float s0 = 0.f, s1 = 0.f, s2 = 0.f, s3 = 0.f;
            #pragma unroll
            for (int cy = 0; cy < 2; ++cy) {
                float yf = y0 + (float)cy;
                if (yf < 0.f || yf > 79.f) continue;
                float wyf = cy ? wy : 1.f - wy;
                int yi = (int)yf;
                #pragma unroll
                for (int cx = 0; cx < 2; ++cx) {
                    float xf = x0 + (float)cx;
                    if (xf < 0.f || xf > 79.f) continue;
                    float wgt = wyf * (cx ? wx : 1.f - wx);
                    int xi = (int)xf;
                    float4 vv = *(const float4*)(vbase + ((size_t)yi * W_ + xi) * 32 + nh * 4);
                    s0 += wgt * vv.x; s1 += wgt * vv.y; s2 += wgt * vv.z; s3 += wgt * vv.w;
                }
            }
            float p = pk[kk];
            a2v[nh * 4 + 0] += p * s0; a2v[nh * 4 + 1] += p * s1;
            a2v[nh * 4 + 2] += p * s2; a2v[nh * 4 + 3] += p * s3;
        }
    }
    float ro[32];
    #pragma unroll
    for (int o = 0; o < 32; ++o) ro[o] = boutL[o];
    for (int c = 0; c < 32; ++c) {
        float ac = a2v[c];
        const float* wr = WoutL + c * 32;
        #pragma unroll
        for (int o = 0; o < 32; ++o) ro[o] += ac * wr[o];
    }
    float* op = a2 + ((size_t)bn * HW_ + hw) * 32;
    #pragma unroll
    for (int i = 0; i < 8; ++i) ((float4*)op)[i] = ((float4*)ro)[i];
}

// ============================================================
// K6: q3/kf/vf projections. R4: weights staged in LDS.
// ============================================================
__global__ __launch_bounds__(256) void k_qkv3(const float* __restrict__ a2,
        const float* __restrict__ Wq3, const float* __restrict__ bq3,
        const float* __restrict__ Wk3, const float* __restrict__ bk3,
        const float* __restrict__ Wv3, const float* __restrict__ bv3,
        float* __restrict__ q3, float* __restrict__ kf, float* __restrict__ vf) {
    __shared__ float Wq3L[1024], Wk3L[1024], Wv3L[1024];
    __shared__ float bq3L[32], bk3L[32], bv3L[32];
    int t = threadIdx.x;
    for (int d = t; d < 1024; d += 256) {
        Wq3L[d] = Wq3[d]; Wk3L[d] = Wk3[d]; Wv3L[d] = Wv3[d];
    }
    if (t < 32) { bq3L[t] = bq3[t]; bk3L[t] = bk3[t]; bv3L[t] = bv3[t]; }
    __syncthreads();
    int idx = blockIdx.x * 256 + t;
    int bn = idx / HW_, hw = idx % HW_;
    int b = bn >> 2, n = bn & 3;
    int ns = (n == 0) ? 0 : n - 1;
    const float* src = a2 + ((size_t)(b * 4 + ns) * HW_ + hw) * 32;
    float v[32];
    #pragma unroll
    for (int i = 0; i < 8; ++i) ((float4*)v)[i] = ((const float4*)src)[i];
    float oq[32], ok[32], ov[32];
    #pragma unroll
    for (int o = 0; o < 32; ++o) {
        float aq = bq3L[o], ak = bk3L[o], av = bv3L[o];
        #pragma unroll
        for (int c = 0; c < 32; ++c) {
            aq += Wq3L[o * 32 + c] * v[c];
            ak += Wk3L[o * 32 + c] * v[c];
            av += Wv3L[o * 32 + c] * v[c];
        }
        oq[o] = aq; ok[o] = ak; ov[o] = av;
    }
    float* qo = q3 + (size_t)idx * 32;
    float* ko = kf + (size_t)idx * 32;
    float* vo = vf + (size_t)idx * 32;
    #pragma unroll
    for (int i = 0; i < 8; ++i) {
        ((float4*)qo)[i] = ((float4*)oq)[i];
        ((float4*)ko)[i] = ((float4*)ok)[i];
        ((float4*)vo)[i] = ((float4*)ov)[i];
    }
}

// ============================================================
// K7: strided conv3d (W_offA) + gelu + W_offB + tanh*OSC -> sample coords
// ============================================================
__global__ __launch_bounds__(256) void k_offs3d(const float* __restrict__ q3,
        const float* __restrict__ WoffA, const float* __restrict__ boffA,
        const float* __restrict__ WoffB, const float* __restrict__ boffB,
        float* __restrict__ coords) {
    __shared__ float red[4][128];
    __shared__ float hidl[128];
    int t = threadIdx.x;
    int blk = blockIdx.x;
    int zo = blk / 100, r = blk % 100, ho = r / 10, wo = r % 10;
    float acc[4][32];
    #pragma unroll
    for (int b = 0; b < 4; ++b)
        #pragma unroll
        for (int o = 0; o < 32; ++o) acc[b][o] = 0.f;
    for (int tap = t; tap < 400; tap += 256) {
        int kz = tap / 100, r2 = tap % 100, ky = r2 / 10, kx = r2 % 10;
        int zi = zo * 2 + kz - 1, hi = ho * 8 + ky - 1, wi = wo * 8 + kx - 1;
        if (zi < 0 || zi >= NIMG_ || hi < 0 || hi >= H_ || wi < 0 || wi >= W_) continue;
        const float* wb = WoffA + tap;
        int sp = hi * W_ + wi;
        for (int c = 0; c < 32; ++c) {
            float vb[4];
            #pragma unroll
            for (int b = 0; b < 4; ++b)
                vb[b] = q3[((size_t)(b * 4 + zi) * HW_ + sp) * 32 + c];
            #pragma unroll
            for (int o = 0; o < 32; ++o) {
                float wv = wb[(o * 32 + c) * 400];
                #pragma unroll
                for (int b = 0; b < 4; ++b) acc[b][o] += vb[b] * wv;
            }
        }
    }
    #pragma unroll
    for (int b = 0; b < 4; ++b)
        #pragma unroll
        for (int o = 0; o < 32; ++o)
            for (int sh = 32; sh >= 1; sh >>= 1)
                acc[b][o] += __shfl_xor(acc[b][o], sh);
    int lane = t & 63, wv = t >> 6;
    if (lane == 0)
        for (int b = 0; b < 4; ++b)
            for (int o = 0; o < 32; ++o) red[wv][b * 32 + o] = acc[b][o];
    __syncthreads();
    if (t < 128) {
        float v = red[0][t] + red[1][t] + red[2][t] + red[3][t] + boffA[t & 31];
        float v3 = v * v * v;
        hidl[t] = 0.5f * v * (1.f + tanhf(0.7978845608028654f * (v + 0.044715f * v3)));
    }
    __syncthreads();
    if (t < 12) {
        int b = t / 3, j = t % 3;
        float a = boffB[j];
        for (int o = 0; o < 32; ++o) a += WoffB[j * 32 + o] * hidl[b * 32 + o];
        float osc = (j == 0) ? 2.f : 8.f;
        float base = (j == 0) ? (zo * 2 + 0.5f) : ((j == 1) ? (ho * 8 + 3.5f) : (wo * 8 + 3.5f));
        coords[((size_t)b * L3_ + blk) * 3 + j] = base + tanhf(a) * osc;
    }
}

// ============================================================
// K8: trilinear sample kf/vf at coords -> ks/vs [b][200][32]
// ============================================================
__global__ __launch_bounds__(256) void k_trisample(const float* __restrict__ kf,
        const float* __restrict__ vf, const float* __restrict__ coords,
        float* __restrict__ ks, float* __restrict__ vs) {
    int t = threadIdx.x;
    int wv = blockIdx.x * 4 + (t >> 6);
    int b = wv / L3_, l = wv % L3_;
    int lane = t & 63;
    int c = lane & 31;
    const float* src = (lane < 32) ? kf : vf;
    float* dst = (lane < 32) ? ks : vs;
    const float* cp = coords + ((size_t)b * L3_ + l) * 3;
    float cz = cp[0], cy = cp[1], cx = cp[2];
    float z0 = floorf(cz), y0 = floorf(cy), x0 = floorf(cx);
    float wz = cz - z0, wy = cy - y0, wx = cx - x0;
    float acc = 0.f;
    #pragma unroll
    for (int dz = 0; dz < 2; ++dz) {
        float zf = z0 + (float)dz;
        if (zf < 0.f || zf > 3.f) continue;
        float wzf = dz ? wz : 1.f - wz;
        int zi = (int)zf;
        #pragma unroll
        for (int dy = 0; dy < 2; ++dy) {
            float yf = y0 + (float)dy;
            if (yf < 0.f || yf > 79.f) continue;
            float wyf = wzf * (dy ? wy : 1.f - wy);
            int yi = (int)yf;
            #pragma unroll
            for (int dx = 0; dx < 2; ++dx) {
                float xf = x0 + (float)dx;
                if (xf < 0.f || xf > 79.f) continue;
                float wgt = wyf * (dx ? wx : 1.f - wx);
                int xi = (int)xf;
                acc += wgt * src[((size_t)(b * 4 + zi) * HW_ + yi * W_ + xi) * 32 + c];
            }
        }
    }
    dst[((size_t)b * L3_ + l) * 32 + c] = acc;
}

// ============================================================
// K9: 25600-query x 200-key attention. R4: single-pass (no max
// subtraction — logits are tiny, softmax is shift-invariant).
// ============================================================
__global__ __launch_bounds__(256) void k_attn3d(const float* __restrict__ q3,
        const float* __restrict__ ks, const float* __restrict__ vs,
        float* __restrict__ o3) {
    __shared__ __align__(16) float ksl[L3_ * 32];
    __shared__ __align__(16) float vsl[L3_ * 32];
    int t = threadIdx.x;
    int b = blockIdx.x / 100;
    int chunk = blockIdx.x % 100;
    const float4* ksg = (const float4*)(ks + (size_t)b * L3_ * 32);
    const float4* vsg = (const float4*)(vs + (size_t)b * L3_ * 32);
    for (int d = t; d < L3_ * 8; d += 256) {
        ((float4*)ksl)[d] = ksg[d];
        ((float4*)vsl)[d] = vsg[d];
    }
    __syncthreads();
    int N = chunk * 256 + t;
    float q[32];
    const float4* qp = (const float4*)(q3 + ((size_t)b * NQ_ + N) * 32);
    #pragma unroll
    for (int i = 0; i < 8; ++i) ((float4*)q)[i] = qp[i];
    const float scale = 0.17677669529663687f;    // 32^-0.5
    float den = 0.f;
    float o[32];
    #pragma unroll
    for (int c = 0; c < 32; ++c) o[c] = 0.f;
    for (int l = 0; l < L3_; ++l) {
        const float4* kp = (const float4*)(ksl + l * 32);
        float s = 0.f;
        #pragma unroll
        for (int c4 = 0; c4 < 8; ++c4) {
            float4 kv = kp[c4];
            s += q[c4 * 4 + 0] * kv.x + q[c4 * 4 + 1] * kv.y + q[c4 * 4 + 2] * kv.z + q[c4 * 4 + 3] * kv.w;
        }
        float p = expf(s * scale);
        den += p;
        const float4* vp = (const float4*)(vsl + l * 32);
        #pragma unroll
        for (int c4 = 0; c4 < 8; ++c4) {
            float4 vv = vp[c4];
            o[c4 * 4 + 0] += p * vv.x; o[c4 * 4 + 1] += p * vv.y;
            o[c4 * 4 + 2] += p * vv.z; o[c4 * 4 + 3] += p * vv.w;
        }
    }
    float inv = 1.f / den;
    float* op = o3 + ((size_t)b * NQ_ + N) * 32;
    #pragma unroll
    for (int c = 0; c < 32; ++c) op[c] = o[c] * inv;
}

// ============================================================
// K10: tiled GEMM  out += r1 * (o3 @ W_out3^T + bias)
// ============================================================
__global__ __launch_bounds__(256) void k_final(const float* __restrict__ o3,
        const float* __restrict__ W, const float* __restrict__ bias,
        const float* __restrict__ r1p, float* __restrict__ out) {
    __shared__ float o3T[32 * 128];     // [k][row]
    __shared__ float WT[32 * 260];      // [k][c]
    int t = threadIdx.x;
    int R0 = blockIdx.x * 128;
    {
        int row = t >> 1, k0 = (t & 1) * 16;
        int R = R0 + row;
        int b = R & 3, N = R >> 2;
        const float* src = o3 + ((size_t)b * NQ_ + N) * 32 + k0;
        #pragma unroll
        for (int j = 0; j < 16; ++j) o3T[(k0 + j) * 128 + row] = src[j];
    }
    for (int d = t; d < 8192; d += 256) {
        int c = d >> 5, k = d & 31;
        WT[k * 260 + c] = W[d];
    }
    __syncthreads();
    int tc = t & 15;
    int tr = t >> 4;
    int r0 = tr * 8;
    float acc[8][16];
    #pragma unroll
    for (int i = 0; i < 8; ++i)
        #pragma unroll
        for (int j = 0; j < 16; ++j) acc[i][j] = 0.f;
    #pragma unroll 1
    for (int k = 0; k < 32; ++k) {
        float a[8];
        *(float4*)&a[0] = *(const float4*)&o3T[k * 128 + r0];
        *(float4*)&a[4] = *(const float4*)&o3T[k * 128 + r0 + 4];
        float wv[16];
        #pragma unroll
        for (int ci = 0; ci < 16; ++ci) wv[ci] = WT[k * 260 + tc + 16 * ci];
        #pragma unroll
        for (int i = 0; i < 8; ++i)
            #pragma unroll
            for (int j = 0; j < 16; ++j) acc[i][j] += a[i] * wv[j];
    }
    float r1 = r1p[0];
    float bs[16];
    #pragma unroll
    for (int ci = 0; ci < 16; ++ci) bs[ci] = bias[tc + 16 * ci];
    #pragma unroll 1
    for (int i = 0; i < 8; ++i) {
        size_t rowbase = (size_t)(R0 + r0 + i) * 256;
        #pragma unroll
        for (int j = 0; j < 16; ++j) {
            size_t oi = rowbase + tc + 16 * j;
            out[oi] = r1 * (acc[i][j] + bs[j]) + out[oi];
        }
    }
}

// ============================================================
extern "C" void kernel_launch(void* const* d_in, const int* in_sizes, int n_in,
                              void* d_out, int out_size, void* d_ws, size_t ws_size,
                              hipStream_t stream) {
    (void)in_sizes; (void)n_in; (void)out_size; (void)ws_size;
    const float* x      = (const float*)d_in[0];
    const float* W_qkv  = (const float*)d_in[1];
    const float* b_qkv  = (const float*)d_in[2];
    const float* W_fc   = (const float*)d_in[3];
    const float* b_fc   = (const float*)d_in[4];
    const float* W_doff = (const float*)d_in[5];
    const float* b_doff = (const float*)d_in[6];
    const float* W_dep  = (const float*)d_in[7];
    const float* b_dep  = (const float*)d_in[8];
    const float* W_st   = (const float*)d_in[9];
    const float* b_st   = (const float*)d_in[10];
    const float* W_off2d= (const float*)d_in[11];
    const float* b_off2d= (const float*)d_in[12];
    const float* W_attw = (const float*)d_in[13];
    const float* b_attw = (const float*)d_in[14];
    const float* W_val  = (const float*)d_in[15];
    const float* b_val  = (const float*)d_in[16];
    const float* W_out2d= (const float*)d_in[17];
    const float* b_out2d= (const float*)d_in[18];
    const float* W_q3   = (const float*)d_in[19];
    const float* b_q3   = (const float*)d_in[20];
    const float* W_k3   = (const float*)d_in[21];
    const float* b_k3   = (const float*)d_in[22];
    const float* W_v3   = (const float*)d_in[23];
    const float* b_v3   = (const float*)d_in[24];
    const float* W_offA = (const float*)d_in[25];
    const float* b_offA = (const float*)d_in[26];
    const float* W_offB = (const float*)d_in[27];
    const float* b_offB = (const float*)d_in[28];
    const float* W_out3 = (const float*)d_in[29];
    const float* b_out3 = (const float*)d_in[30];
    const float* rate1  = (const float*)d_in[31];
    const float* rate2  = (const float*)d_in[32];

    float* ws  = (float*)d_ws;
    float* out = (float*)d_out;
    float* qkv = ws + WS_QKV;
    float* fin = ws + WS_FIN;
    float* off = ws + WS_OFF;
    float* v2  = ws + WS_V2;
    float* a2  = ws + WS_A2;
    float* q3  = ws + WS_Q3;
    float* kf  = ws + WS_KF;
    float* vf  = ws + WS_VF;
    float* crd = ws + WS_CRD;
    float* ks  = ws + WS_KS;
    float* vs  = ws + WS_VS;
    float* o3w = ws + WS_O3;

    k_qkv      <<<3200,   256, 0, stream>>>(x, W_qkv, b_qkv, qkv);
    k_fin_v2   <<<400,    256, 0, stream>>>(qkv, W_fc, b_fc, W_val, b_val, fin, v2);
    k_offconv  <<<400,    256, 0, stream>>>(fin, W_doff, b_doff, off);
    k_depst    <<<1600,   256, 0, stream>>>(fin, off, W_dep, b_dep, W_st, b_st, rate2, out);
    k_attn2d   <<<400,    256, 0, stream>>>(qkv, v2, W_off2d, b_off2d, W_attw, b_attw, W_out2d, b_out2d, a2);
    k_qkv3     <<<400,    256, 0, stream>>>(a2, W_q3, b_q3, W_k3, b_k3, W_v3, b_v3, q3, kf, vf);
    k_offs3d   <<<200,    256, 0, stream>>>(q3, W_offA, b_offA, W_offB, b_offB, crd);
    k_trisample<<<200,    256, 0, stream>>>(kf, vf, crd, ks, vs);
    k_attn3d   <<<400,    256, 0, stream>>>(q3, ks, vs, o3w);
    k_final    <<<800,    256, 0, stream>>>(o3w, W_out3, b_out3, rate1, out);
}